// Round 1
// baseline (1710.149 us; speedup 1.0000x reference)
//
#include <hip/hip_runtime.h>
#include <hip/hip_bf16.h>
#include <math.h>

#define C 128
#define HH 8
#define DD 16

__device__ __forceinline__ float gelu_exact(float x) {
    return 0.5f * x * (1.0f + erff(x * 0.70710678118654752f));
}

// ---------------- GEMM: C = act(A[MxK] @ W[Kx128] + bias) ----------------
// MODE 0: none; MODE 1: relu; MODE 2: gelu applied to A on load, epilogue
//         out = beta*(acc+bias) + (1-beta)*hprev  (beta = sigmoid(*skipp))
template <int K, int MODE>
__global__ __launch_bounds__(256) void gemm_kernel(
    const float* __restrict__ A, const float* __restrict__ W,
    const float* __restrict__ bias, float* __restrict__ Cout, int M,
    const float* __restrict__ hprev, const float* __restrict__ skipp) {
    __shared__ float As[64][17];
    __shared__ float Bs[16][128];
    const int tid = threadIdx.x;
    const int tx = tid & 31;        // col group: cols 4*tx .. 4*tx+3
    const int ty = tid >> 5;        // row group: rows ty*8 .. ty*8+7
    const int row0 = blockIdx.x * 64;
    float acc[8][4];
#pragma unroll
    for (int i = 0; i < 8; ++i)
#pragma unroll
        for (int j = 0; j < 4; ++j) acc[i][j] = 0.f;

    for (int kb = 0; kb < K; kb += 16) {
        // stage A tile 64x16 (float4 per thread)
        {
            int r = tid >> 2;
            int kq = (tid & 3) * 4;
            int gr = row0 + r;
            float4 v = make_float4(0.f, 0.f, 0.f, 0.f);
            if (gr < M) v = *reinterpret_cast<const float4*>(A + (size_t)gr * K + kb + kq);
            if (MODE == 2) {
                v.x = gelu_exact(v.x); v.y = gelu_exact(v.y);
                v.z = gelu_exact(v.z); v.w = gelu_exact(v.w);
            }
            As[r][kq + 0] = v.x; As[r][kq + 1] = v.y;
            As[r][kq + 2] = v.z; As[r][kq + 3] = v.w;
        }
        // stage B tile 16x128 (2x float4 per thread)
#pragma unroll
        for (int i = 0; i < 2; ++i) {
            int t4 = tid + i * 256;           // 0..511
            int kk = t4 >> 5;                 // 0..15
            int col4 = (t4 & 31) * 4;
            float4 v = *reinterpret_cast<const float4*>(W + (size_t)(kb + kk) * 128 + col4);
            Bs[kk][col4 + 0] = v.x; Bs[kk][col4 + 1] = v.y;
            Bs[kk][col4 + 2] = v.z; Bs[kk][col4 + 3] = v.w;
        }
        __syncthreads();
#pragma unroll
        for (int kk = 0; kk < 16; ++kk) {
            float4 b = *reinterpret_cast<const float4*>(&Bs[kk][tx * 4]);
#pragma unroll
            for (int i = 0; i < 8; ++i) {
                float a = As[ty * 8 + i][kk];
                acc[i][0] += a * b.x; acc[i][1] += a * b.y;
                acc[i][2] += a * b.z; acc[i][3] += a * b.w;
            }
        }
        __syncthreads();
    }
    float beta = 0.f;
    if (MODE == 2) beta = 1.f / (1.f + expf(-skipp[0]));
#pragma unroll
    for (int i = 0; i < 8; ++i) {
        int gr = row0 + ty * 8 + i;
        if (gr >= M) continue;
#pragma unroll
        for (int j = 0; j < 4; ++j) {
            int col = tx * 4 + j;
            float v = acc[i][j] + bias[col];
            if (MODE == 1) v = fmaxf(v, 0.f);
            if (MODE == 2) v = beta * v + (1.f - beta) * hprev[(size_t)gr * 128 + col];
            Cout[(size_t)gr * 128 + col] = v;
        }
    }
}

// ------------- fold relation transform into weights -------------
// Wf[i][h*16+f] = sum_d W[i][h*16+d] * arel[h][d][f]; row 128 folds bias.
__global__ void fold_kernel(const float* __restrict__ W, const float* __restrict__ b,
                            const float* __restrict__ arel, float* __restrict__ Wf,
                            float* __restrict__ bf) {
    int gid = blockIdx.x * 256 + threadIdx.x;
    if (gid >= 129 * 128) return;
    int i = gid >> 7, col = gid & 127;
    int h = col >> 4, f = col & 15;
    const float* srcrow = (i < 128) ? (W + (size_t)i * 128) : b;
    float s = 0.f;
#pragma unroll
    for (int d = 0; d < 16; ++d) s += srcrow[h * 16 + d] * arel[h * 256 + d * 16 + f];
    if (i < 128) Wf[(size_t)i * 128 + col] = s;
    else bf[col] = s;
}

// ------------- CSR build -------------
__global__ void hist_kernel(const int* __restrict__ dst, int* __restrict__ cnt, int E) {
    int e = blockIdx.x * 256 + threadIdx.x;
    if (e < E) atomicAdd(&cnt[dst[e]], 1);
}

__global__ __launch_bounds__(1024) void scanA_kernel(const int* __restrict__ cnt,
                                                     int* __restrict__ texcl,
                                                     int* __restrict__ bsums, int n) {
    __shared__ int s[1024];
    int t = threadIdx.x;
    int gid = blockIdx.x * 1024 + t;
    int x = (gid < n) ? cnt[gid] : 0;
    s[t] = x;
    __syncthreads();
    for (int off = 1; off < 1024; off <<= 1) {
        int v = (t >= off) ? s[t - off] : 0;
        __syncthreads();
        s[t] += v;
        __syncthreads();
    }
    if (gid < n) texcl[gid] = s[t] - x;
    if (t == 1023) bsums[blockIdx.x] = s[1023];
}

__global__ void scanB_kernel(int* bsums, int nb) {
    if (threadIdx.x == 0 && blockIdx.x == 0) {
        int run = 0;
        for (int i = 0; i < nb; ++i) { int t = bsums[i]; bsums[i] = run; run += t; }
    }
}

__global__ __launch_bounds__(1024) void scanC_kernel(const int* __restrict__ texcl,
                                                     const int* __restrict__ bsums,
                                                     int* __restrict__ indptr,
                                                     int* __restrict__ cursor, int n, int E) {
    int gid = blockIdx.x * 1024 + threadIdx.x;
    if (gid < n) {
        int v = texcl[gid] + bsums[blockIdx.x];
        indptr[gid] = v;
        cursor[gid] = v;
    }
    if (gid == 0) indptr[n] = E;
}

__global__ void scatter_kernel(const int* __restrict__ src, const int* __restrict__ dst,
                               int* __restrict__ cursor, int* __restrict__ ssrc, int E) {
    int e = blockIdx.x * 256 + threadIdx.x;
    if (e < E) {
        int p = atomicAdd(&cursor[dst[e]], 1);
        ssrc[p] = src[e];
    }
}

// ------------- attention: one wave per destination node -------------
template <int ACC>
__global__ __launch_bounds__(256) void attn_kernel(
    const float* __restrict__ qd, const float* __restrict__ kr,
    const float* __restrict__ vr, const int* __restrict__ indptr,
    const int* __restrict__ ssrc, float* __restrict__ alpha_buf,
    float* __restrict__ agg, const float* __restrict__ prel, int Nd) {
    int wave = (blockIdx.x * blockDim.x + threadIdx.x) >> 6;
    int lane = threadIdx.x & 63;
    if (wave >= Nd) return;
    const int dst = wave;
    const int h = lane >> 3, j = lane & 7;
    const float p = prel[h] * 0.25f;  // * 1/sqrt(D)
    float2 q2 = *reinterpret_cast<const float2*>(qd + (size_t)dst * 128 + lane * 2);
    int beg = indptr[dst], end = indptr[dst + 1];
    float m = -INFINITY, ssum = 0.f;
    for (int i = beg; i < end; ++i) {
        int src = ssrc[i];
        float2 k2 = *reinterpret_cast<const float2*>(kr + (size_t)src * 128 + lane * 2);
        float t = q2.x * k2.x + q2.y * k2.y;
        t += __shfl_xor(t, 1);
        t += __shfl_xor(t, 2);
        t += __shfl_xor(t, 4);
        float alpha = t * p;
        if (j == 0) alpha_buf[(size_t)i * 8 + h] = alpha;
        float nm = fmaxf(m, alpha);
        ssum = ssum * expf(m - nm) + expf(alpha - nm);
        m = nm;
    }
    float inv = 1.f / fmaxf(ssum, 1e-16f);
    float ax = 0.f, ay = 0.f;
    for (int i = beg; i < end; ++i) {
        int src = ssrc[i];
        float a = alpha_buf[(size_t)i * 8 + h];
        float w = expf(a - m) * inv;
        float2 v2 = *reinterpret_cast<const float2*>(vr + (size_t)src * 128 + lane * 2);
        ax += w * v2.x;
        ay += w * v2.y;
    }
    float* dp = agg + (size_t)dst * 128 + lane * 2;
    if (ACC) { dp[0] += ax; dp[1] += ay; }
    else { dp[0] = ax; dp[1] = ay; }
}

// ------------- readout -------------
__global__ void colsum_kernel(const float* __restrict__ h, float* __restrict__ gsum, int M) {
    int c = threadIdx.x;  // 128 threads
    float s = 0.f;
    for (int r = blockIdx.x; r < M; r += gridDim.x) s += h[(size_t)r * 128 + c];
    atomicAdd(&gsum[c], s);
}

__global__ void final_kernel(const float* __restrict__ gsum, const float* __restrict__ Wc1,
                             const float* __restrict__ bc1, const float* __restrict__ Wc2,
                             const float* __restrict__ bc2, float* __restrict__ out,
                             float invM) {
    __shared__ float g[128];
    __shared__ float red[128];
    int t = threadIdx.x;  // 128
    g[t] = gsum[t] * invM;
    __syncthreads();
    float acc = bc1[t];
    for (int k = 0; k < 128; ++k) acc += g[k] * Wc1[k * 128 + t];
    float zv = fmaxf(acc, 0.f);
    red[t] = zv * Wc2[t];
    __syncthreads();
    for (int off = 64; off > 0; off >>= 1) {
        if (t < off) red[t] += red[t + off];
        __syncthreads();
    }
    if (t == 0) out[0] = 1.f / (1.f + expf(-(red[0] + bc2[0])));
}

extern "C" void kernel_launch(void* const* d_in, const int* in_sizes, int n_in,
                              void* d_out, int out_size, void* d_ws, size_t ws_size,
                              hipStream_t stream) {
    const float* x[2] = {(const float*)d_in[0], (const float*)d_in[1]};
    const int* edges[3] = {(const int*)d_in[2], (const int*)d_in[3], (const int*)d_in[4]};
    const float* Win[2] = {(const float*)d_in[5], (const float*)d_in[7]};
    const float* bin[2] = {(const float*)d_in[6], (const float*)d_in[8]};
    const float* Wk = (const float*)d_in[9];
    const float* bk = (const float*)d_in[10];
    const float* Wq = (const float*)d_in[11];
    const float* bq = (const float*)d_in[12];
    const float* Wv = (const float*)d_in[13];
    const float* bv = (const float*)d_in[14];
    const float* a_rel = (const float*)d_in[15];
    const float* m_rel = (const float*)d_in[16];
    const float* p_rel = (const float*)d_in[17];
    const float* Wa = (const float*)d_in[18];
    const float* ba = (const float*)d_in[19];
    const float* skip = (const float*)d_in[20];
    const float* Wc1 = (const float*)d_in[21];
    const float* bc1 = (const float*)d_in[22];
    const float* Wc2 = (const float*)d_in[23];
    const float* bc2 = (const float*)d_in[24];

    const int N0 = in_sizes[0] / 64;
    const int N1 = in_sizes[1] / 64;
    const int E = in_sizes[2] / 2;
    const int L = in_sizes[9] / (2 * 128 * 128);
    const int Ns[2] = {N0, N1};
    const int RS[3] = {0, 1, 0}, RD[3] = {0, 0, 1};

    // ---- carve workspace ----
    char* p = (char*)d_ws;
    auto alloc = [&](size_t bytes) -> void* {
        void* r = (void*)p;
        p += (bytes + 255) & ~(size_t)255;
        return r;
    };
    float* h[2];  float* q[2];  float* agg[2];
    h[0] = (float*)alloc((size_t)N0 * 128 * 4);
    h[1] = (float*)alloc((size_t)N1 * 128 * 4);
    q[0] = (float*)alloc((size_t)N0 * 128 * 4);
    q[1] = (float*)alloc((size_t)N1 * 128 * 4);
    agg[0] = (float*)alloc((size_t)N0 * 128 * 4);
    agg[1] = (float*)alloc((size_t)N1 * 128 * 4);
    float* kr = (float*)alloc((size_t)((N0 > N1) ? N0 : N1) * 128 * 4);
    float* vr = (float*)alloc((size_t)((N0 > N1) ? N0 : N1) * 128 * 4);
    float* alpha = (float*)alloc((size_t)E * 8 * 4);
    int* indptr[3]; int* ssrc[3];
    for (int r = 0; r < 3; ++r) {
        indptr[r] = (int*)alloc((size_t)(Ns[RD[r]] + 1) * 4);
        ssrc[r] = (int*)alloc((size_t)E * 4);
    }
    int* cnt = (int*)alloc((size_t)((N0 > N1) ? N0 : N1) * 4);   // also cursor
    int* texcl = (int*)alloc((size_t)((N0 > N1) ? N0 : N1) * 4);
    int* bsums = (int*)alloc(256 * 4);
    float* wfk = (float*)alloc(128 * 128 * 4);
    float* bfk = (float*)alloc(128 * 4);
    float* wfv = (float*)alloc(128 * 128 * 4);
    float* bfv = (float*)alloc(128 * 4);
    float* gsum = (float*)alloc(128 * 4);

    // ---- CSR build (once; reused across layers) ----
    for (int r = 0; r < 3; ++r) {
        int Nd = Ns[RD[r]];
        int nb = (Nd + 1023) / 1024;
        hipMemsetAsync(cnt, 0, (size_t)Nd * 4, stream);
        hist_kernel<<<(E + 255) / 256, 256, 0, stream>>>(edges[r] + E, cnt, E);
        scanA_kernel<<<nb, 1024, 0, stream>>>(cnt, texcl, bsums, Nd);
        scanB_kernel<<<1, 64, 0, stream>>>(bsums, nb);
        scanC_kernel<<<nb, 1024, 0, stream>>>(texcl, bsums, indptr[r], cnt, Nd, E);
        scatter_kernel<<<(E + 255) / 256, 256, 0, stream>>>(edges[r], edges[r] + E, cnt,
                                                            ssrc[r], E);
    }

    // ---- input projection: h[t] = relu(x @ Win + bin) ----
    for (int t = 0; t < 2; ++t) {
        gemm_kernel<64, 1><<<(Ns[t] + 63) / 64, 256, 0, stream>>>(
            x[t], Win[t], bin[t], h[t], Ns[t], nullptr, nullptr);
    }

    // ---- layers ----
    for (int l = 0; l < L; ++l) {
        // q per type
        for (int t = 0; t < 2; ++t) {
            const float* Wq_lt = Wq + (size_t)(l * 2 + t) * 128 * 128;
            const float* bq_lt = bq + (size_t)(l * 2 + t) * 128;
            gemm_kernel<128, 0><<<(Ns[t] + 63) / 64, 256, 0, stream>>>(
                h[t], Wq_lt, bq_lt, q[t], Ns[t], nullptr, nullptr);
        }
        for (int r = 0; r < 3; ++r) {
            int s = RS[r], d = RD[r];
            const float* Wk_ls = Wk + (size_t)(l * 2 + s) * 128 * 128;
            const float* bk_ls = bk + (size_t)(l * 2 + s) * 128;
            const float* Wv_ls = Wv + (size_t)(l * 2 + s) * 128 * 128;
            const float* bv_ls = bv + (size_t)(l * 2 + s) * 128;
            const float* a_lr = a_rel + (size_t)(l * 3 + r) * 8 * 16 * 16;
            const float* m_lr = m_rel + (size_t)(l * 3 + r) * 8 * 16 * 16;
            const float* p_lr = p_rel + (size_t)(l * 3 + r) * 8;
            fold_kernel<<<65, 256, 0, stream>>>(Wk_ls, bk_ls, a_lr, wfk, bfk);
            fold_kernel<<<65, 256, 0, stream>>>(Wv_ls, bv_ls, m_lr, wfv, bfv);
            gemm_kernel<128, 0><<<(Ns[s] + 63) / 64, 256, 0, stream>>>(
                h[s], wfk, bfk, kr, Ns[s], nullptr, nullptr);
            gemm_kernel<128, 0><<<(Ns[s] + 63) / 64, 256, 0, stream>>>(
                h[s], wfv, bfv, vr, Ns[s], nullptr, nullptr);
            int Nd = Ns[d];
            dim3 grid((Nd + 3) / 4);
            if (r == 1)
                attn_kernel<1><<<grid, 256, 0, stream>>>(q[d], kr, vr, indptr[r], ssrc[r],
                                                         alpha, agg[d], p_lr, Nd);
            else
                attn_kernel<0><<<grid, 256, 0, stream>>>(q[d], kr, vr, indptr[r], ssrc[r],
                                                         alpha, agg[d], p_lr, Nd);
        }
        // out = beta*(gelu(agg)@Wa + ba) + (1-beta)*h  (in place on h)
        for (int t = 0; t < 2; ++t) {
            const float* Wa_lt = Wa + (size_t)(l * 2 + t) * 128 * 128;
            const float* ba_lt = ba + (size_t)(l * 2 + t) * 128;
            const float* skip_lt = skip + (size_t)(l * 2 + t);
            gemm_kernel<128, 2><<<(Ns[t] + 63) / 64, 256, 0, stream>>>(
                agg[t], Wa_lt, ba_lt, h[t], Ns[t], h[t], skip_lt);
        }
    }

    // ---- readout ----
    hipMemsetAsync(gsum, 0, 128 * 4, stream);
    colsum_kernel<<<512, 128, 0, stream>>>(h[0], gsum, N0);
    final_kernel<<<1, 128, 0, stream>>>(gsum, Wc1, bc1, Wc2, bc2, (float*)d_out,
                                        1.0f / (float)N0);
}

// Round 2
// 999.243 us; speedup vs baseline: 1.7114x; 1.7114x over previous
//
#include <hip/hip_runtime.h>
#include <math.h>

typedef __attribute__((ext_vector_type(8))) short short8v;   // 8 x bf16 (4 VGPRs)
typedef __attribute__((ext_vector_type(4))) float f32x4;

__device__ __forceinline__ float bf2f(unsigned short u) {
    union { unsigned int i; float f; } x; x.i = ((unsigned int)u) << 16; return x.f;
}
__device__ __forceinline__ unsigned short f2bf(float f) {
    union { float f; unsigned int i; } x; x.f = f;
    unsigned int r = x.i + 0x7fffu + ((x.i >> 16) & 1u);
    return (unsigned short)(r >> 16);
}
__device__ __forceinline__ float gelu_exact(float x) {
    return 0.5f * x * (1.0f + erff(x * 0.70710678118654752f));
}

// ============ bf16 MFMA GEMM: C[M x 128] = act(A[M x K] @ B[K x 128] + bias) ============
// B passed as BT (bf16, [128][K] row-major). Output bf16.
// MODE 0: none; 1: relu on output; 2: gelu on A-load + skip blend epilogue.
// ASRC 0: A is bf16 [M][K]; 1: A is fp32 [M][K].
template <int K, int MODE, int ASRC>
__global__ __launch_bounds__(256) void gemm_mfma(
    const void* __restrict__ Aptr, const unsigned short* __restrict__ BT,
    const float* __restrict__ bias, unsigned short* __restrict__ Cout, int M,
    const unsigned short* __restrict__ hprev, const float* __restrict__ skipp) {
    __shared__ short As[128 * K];
    __shared__ short Bs[128 * K];
    const int tid = threadIdx.x;
    const int row0 = blockIdx.x * 128;
    const int CH = K / 8;  // 16B chunks per row

    // ---- stage A (swizzled: byte ^= (row&7)<<4) ----
#pragma unroll
    for (int i = 0; i < (128 * CH) / 256; ++i) {
        int idx = tid + i * 256;
        int r = idx / CH, c = idx % CH;
        int gr = row0 + r;
        short8v val = {0, 0, 0, 0, 0, 0, 0, 0};
        if (gr < M) {
            if (ASRC == 0) {
                val = *reinterpret_cast<const short8v*>(
                    (const unsigned short*)Aptr + (size_t)gr * K + c * 8);
            } else {
                const float* Af = (const float*)Aptr;
                float4 f0 = *reinterpret_cast<const float4*>(Af + (size_t)gr * K + c * 8);
                float4 f1 = *reinterpret_cast<const float4*>(Af + (size_t)gr * K + c * 8 + 4);
                float fa[8] = {f0.x, f0.y, f0.z, f0.w, f1.x, f1.y, f1.z, f1.w};
#pragma unroll
                for (int u = 0; u < 8; ++u) {
                    float fv = fa[u];
                    if (MODE == 2) fv = gelu_exact(fv);
                    val[u] = (short)f2bf(fv);
                }
            }
        }
        *reinterpret_cast<short8v*>((char*)As + r * (2 * K) + ((c * 16) ^ ((r & 7) << 4))) = val;
    }
    // ---- stage BT ----
#pragma unroll
    for (int i = 0; i < (128 * CH) / 256; ++i) {
        int idx = tid + i * 256;
        int r = idx / CH, c = idx % CH;
        short8v val = *reinterpret_cast<const short8v*>(BT + (size_t)r * K + c * 8);
        *reinterpret_cast<short8v*>((char*)Bs + r * (2 * K) + ((c * 16) ^ ((r & 7) << 4))) = val;
    }
    __syncthreads();

    const int lane = tid & 63, wid = tid >> 6;
    const int wr = wid >> 1, wc = wid & 1;      // 2x2 wave grid, 64x64 per wave
    const int lr = lane & 15, lg = lane >> 4;
    const int swz = (lr & 7) << 4;
    f32x4 acc[4][4];
    f32x4 z4 = {0.f, 0.f, 0.f, 0.f};
#pragma unroll
    for (int mi = 0; mi < 4; ++mi)
#pragma unroll
        for (int ni = 0; ni < 4; ++ni) acc[mi][ni] = z4;

#pragma unroll
    for (int ks = 0; ks < K / 32; ++ks) {
        int kc = ks * 64 + lg * 16;  // byte offset of this lane-group's 8 bf16
        short8v a[4], b[4];
#pragma unroll
        for (int mi = 0; mi < 4; ++mi) {
            int r = wr * 64 + mi * 16 + lr;
            a[mi] = *reinterpret_cast<const short8v*>((char*)As + r * (2 * K) + (kc ^ swz));
        }
#pragma unroll
        for (int ni = 0; ni < 4; ++ni) {
            int r = wc * 64 + ni * 16 + lr;
            b[ni] = *reinterpret_cast<const short8v*>((char*)Bs + r * (2 * K) + (kc ^ swz));
        }
#pragma unroll
        for (int mi = 0; mi < 4; ++mi)
#pragma unroll
            for (int ni = 0; ni < 4; ++ni)
                acc[mi][ni] =
                    __builtin_amdgcn_mfma_f32_16x16x32_bf16(a[mi], b[ni], acc[mi][ni], 0, 0, 0);
    }

    float beta = 0.f;
    if (MODE == 2) beta = 1.f / (1.f + expf(-skipp[0]));
#pragma unroll
    for (int mi = 0; mi < 4; ++mi) {
#pragma unroll
        for (int ni = 0; ni < 4; ++ni) {
            int col = wc * 64 + ni * 16 + lr;
            float bv = bias[col];
#pragma unroll
            for (int j = 0; j < 4; ++j) {
                int gr = row0 + wr * 64 + mi * 16 + lg * 4 + j;
                if (gr < M) {
                    float v = acc[mi][ni][j] + bv;
                    if (MODE == 1) v = fmaxf(v, 0.f);
                    if (MODE == 2) v = beta * v + (1.f - beta) * bf2f(hprev[(size_t)gr * 128 + col]);
                    Cout[(size_t)gr * 128 + col] = f2bf(v);
                }
            }
        }
    }
}

// ============ weight prep: transpose + bf16 convert ============
// winT: 2 mats [128][64]; wqT: nmat mats [128][128]; waT: nmat mats [128][128]
__global__ void convT_kernel(const float* __restrict__ Win0, const float* __restrict__ Win1,
                             const float* __restrict__ Wq, const float* __restrict__ Wa,
                             unsigned short* __restrict__ winT, unsigned short* __restrict__ wqT,
                             unsigned short* __restrict__ waT, int nmat) {
    int gid = blockIdx.x * 256 + threadIdx.x;
    if (gid < 2 * 8192) {
        int m = gid >> 13, idx = gid & 8191;
        int n = idx >> 6, k = idx & 63;
        const float* W = m ? Win1 : Win0;
        winT[gid] = f2bf(W[(size_t)k * 128 + n]);
        return;
    }
    int g = gid - 2 * 8192;
    if (g < nmat * 16384) {
        int mat = g >> 14, idx = g & 16383;
        int n = idx >> 7, k = idx & 127;
        wqT[g] = f2bf(Wq[(size_t)mat * 16384 + (size_t)k * 128 + n]);
        return;
    }
    g -= nmat * 16384;
    if (g < nmat * 16384) {
        int mat = g >> 14, idx = g & 16383;
        int n = idx >> 7, k = idx & 127;
        waT[g] = f2bf(Wa[(size_t)mat * 16384 + (size_t)k * 128 + n]);
    }
}

// ============ relation fold: WfT[fold][col][i] = sum_d W[i][h*16+d]*rel[h][d][f] ============
// fold = (l*3+r)*2 + kv ; col = h*16+f. Also folded biases (fp32).
__global__ void fold_kernel(const float* __restrict__ Wk, const float* __restrict__ bk,
                            const float* __restrict__ Wv, const float* __restrict__ bv,
                            const float* __restrict__ a_rel, const float* __restrict__ m_rel,
                            unsigned short* __restrict__ wfT, float* __restrict__ bfold, int L) {
    const int RSarr[3] = {0, 1, 0};
    int gid = blockIdx.x * 256 + threadIdx.x;
    int NW = L * 6 * 16384;
    if (gid < NW) {
        int fold = gid >> 14, idx = gid & 16383;
        int col = idx >> 7, i = idx & 127;
        int kv = fold & 1, lr = fold >> 1, l = lr / 3, r = lr % 3;
        int s = RSarr[r];
        const float* W = (kv ? Wv : Wk) + (size_t)(l * 2 + s) * 16384;
        const float* rel = (kv ? m_rel : a_rel) + (size_t)(l * 3 + r) * 2048;
        int hh = col >> 4, f = col & 15;
        float sacc = 0.f;
#pragma unroll
        for (int d = 0; d < 16; ++d) sacc += W[(size_t)i * 128 + hh * 16 + d] * rel[hh * 256 + d * 16 + f];
        wfT[gid] = f2bf(sacc);
        return;
    }
    int g = gid - NW;
    if (g >= L * 6 * 128) return;
    int fold = g >> 7, col = g & 127;
    int kv = fold & 1, lr = fold >> 1, l = lr / 3, r = lr % 3;
    int s = RSarr[r];
    const float* b = (kv ? bv : bk) + (size_t)(l * 2 + s) * 128;
    const float* rel = (kv ? m_rel : a_rel) + (size_t)(l * 3 + r) * 2048;
    int hh = col >> 4, f = col & 15;
    float sacc = 0.f;
#pragma unroll
    for (int d = 0; d < 16; ++d) sacc += b[hh * 16 + d] * rel[hh * 256 + d * 16 + f];
    bfold[fold * 128 + col] = sacc;
}

// ============ CSR build ============
__global__ void hist_kernel(const int* __restrict__ dst, int* __restrict__ cnt, int E) {
    int e = blockIdx.x * 256 + threadIdx.x;
    if (e < E) atomicAdd(&cnt[dst[e]], 1);
}

__global__ __launch_bounds__(1024) void scanA_kernel(const int* __restrict__ cnt,
                                                     int* __restrict__ texcl,
                                                     int* __restrict__ bsums, int n) {
    __shared__ int s[1024];
    int t = threadIdx.x;
    int gid = blockIdx.x * 1024 + t;
    int x = (gid < n) ? cnt[gid] : 0;
    s[t] = x;
    __syncthreads();
    for (int off = 1; off < 1024; off <<= 1) {
        int v = (t >= off) ? s[t - off] : 0;
        __syncthreads();
        s[t] += v;
        __syncthreads();
    }
    if (gid < n) texcl[gid] = s[t] - x;
    if (t == 1023) bsums[blockIdx.x] = s[1023];
}

__global__ void scanB_kernel(int* bsums, int nb) {
    if (threadIdx.x == 0 && blockIdx.x == 0) {
        int run = 0;
        for (int i = 0; i < nb; ++i) { int t = bsums[i]; bsums[i] = run; run += t; }
    }
}

__global__ __launch_bounds__(1024) void scanC_kernel(const int* __restrict__ texcl,
                                                     const int* __restrict__ bsums,
                                                     int* __restrict__ indptr,
                                                     int* __restrict__ cursor, int n, int E) {
    int gid = blockIdx.x * 1024 + threadIdx.x;
    if (gid < n) {
        int v = texcl[gid] + bsums[blockIdx.x];
        indptr[gid] = v;
        cursor[gid] = v;
    }
    if (gid == 0) indptr[n] = E;
}

__global__ void scatter_kernel(const int* __restrict__ src, const int* __restrict__ dst,
                               int* __restrict__ cursor, int* __restrict__ ssrc, int E) {
    int e = blockIdx.x * 256 + threadIdx.x;
    if (e < E) {
        int p = atomicAdd(&cursor[dst[e]], 1);
        ssrc[p] = src[e];
    }
}

// ============ attention: single-pass online softmax, one wave per dst ============
template <int ACC>
__global__ __launch_bounds__(256) void attn_kernel(
    const unsigned short* __restrict__ qd, const unsigned short* __restrict__ kr,
    const unsigned short* __restrict__ vr, const int* __restrict__ indptr,
    const int* __restrict__ ssrc, float* __restrict__ agg,
    const float* __restrict__ prel, int Nd) {
    int wave = (blockIdx.x * blockDim.x + threadIdx.x) >> 6;
    int lane = threadIdx.x & 63;
    if (wave >= Nd) return;
    const int h = lane >> 3;
    const float p = prel[h] * 0.25f;  // * 1/sqrt(D)
    ushort2 q2 = *reinterpret_cast<const ushort2*>(qd + (size_t)wave * 128 + lane * 2);
    float qx = bf2f(q2.x), qy = bf2f(q2.y);
    int beg = indptr[wave], end = indptr[wave + 1];
    float m = -INFINITY, ssum = 0.f, ax = 0.f, ay = 0.f;
    for (int i = beg; i < end; ++i) {
        int src = ssrc[i];
        ushort2 k2 = *reinterpret_cast<const ushort2*>(kr + (size_t)src * 128 + lane * 2);
        ushort2 v2 = *reinterpret_cast<const ushort2*>(vr + (size_t)src * 128 + lane * 2);
        float t = qx * bf2f(k2.x) + qy * bf2f(k2.y);
        t += __shfl_xor(t, 1);
        t += __shfl_xor(t, 2);
        t += __shfl_xor(t, 4);
        float alpha = t * p;
        float nm = fmaxf(m, alpha);
        float sc = __expf(m - nm);   // 0 on first edge (m=-inf)
        float w = __expf(alpha - nm);
        ssum = ssum * sc + w;
        ax = ax * sc + w * bf2f(v2.x);
        ay = ay * sc + w * bf2f(v2.y);
        m = nm;
    }
    float inv = 1.f / fmaxf(ssum, 1e-16f);
    float* dp = agg + (size_t)wave * 128 + lane * 2;
    if (ACC) { dp[0] += ax * inv; dp[1] += ay * inv; }
    else { dp[0] = ax * inv; dp[1] = ay * inv; }
}

// ============ readout ============
__global__ void colsum_kernel(const unsigned short* __restrict__ h, float* __restrict__ gsum,
                              int M) {
    int c = threadIdx.x;  // 128 threads
    float s = 0.f;
    for (int r = blockIdx.x; r < M; r += gridDim.x) s += bf2f(h[(size_t)r * 128 + c]);
    atomicAdd(&gsum[c], s);
}

__global__ void final_kernel(const float* __restrict__ gsum, const float* __restrict__ Wc1,
                             const float* __restrict__ bc1, const float* __restrict__ Wc2,
                             const float* __restrict__ bc2, float* __restrict__ out,
                             float invM) {
    __shared__ float g[128];
    __shared__ float red[128];
    int t = threadIdx.x;  // 128
    g[t] = gsum[t] * invM;
    __syncthreads();
    float acc = bc1[t];
    for (int k = 0; k < 128; ++k) acc += g[k] * Wc1[k * 128 + t];
    float zv = fmaxf(acc, 0.f);
    red[t] = zv * Wc2[t];
    __syncthreads();
    for (int off = 64; off > 0; off >>= 1) {
        if (t < off) red[t] += red[t + off];
        __syncthreads();
    }
    if (t == 0) out[0] = 1.f / (1.f + expf(-(red[0] + bc2[0])));
}

extern "C" void kernel_launch(void* const* d_in, const int* in_sizes, int n_in,
                              void* d_out, int out_size, void* d_ws, size_t ws_size,
                              hipStream_t stream) {
    const float* x[2] = {(const float*)d_in[0], (const float*)d_in[1]};
    const int* edges[3] = {(const int*)d_in[2], (const int*)d_in[3], (const int*)d_in[4]};
    const float* Win[2] = {(const float*)d_in[5], (const float*)d_in[7]};
    const float* bin[2] = {(const float*)d_in[6], (const float*)d_in[8]};
    const float* Wk = (const float*)d_in[9];
    const float* bk = (const float*)d_in[10];
    const float* Wq = (const float*)d_in[11];
    const float* bq = (const float*)d_in[12];
    const float* Wv = (const float*)d_in[13];
    const float* bv = (const float*)d_in[14];
    const float* a_rel = (const float*)d_in[15];
    const float* m_rel = (const float*)d_in[16];
    const float* p_rel = (const float*)d_in[17];
    const float* Wa = (const float*)d_in[18];
    const float* ba = (const float*)d_in[19];
    const float* skip = (const float*)d_in[20];
    const float* Wc1 = (const float*)d_in[21];
    const float* bc1 = (const float*)d_in[22];
    const float* Wc2 = (const float*)d_in[23];
    const float* bc2 = (const float*)d_in[24];

    const int N0 = in_sizes[0] / 64;
    const int N1 = in_sizes[1] / 64;
    const int L = in_sizes[9] / (2 * 128 * 128);
    const int Ns[2] = {N0, N1};
    const int RS[3] = {0, 1, 0}, RD[3] = {0, 0, 1};
    const int Nmax = (N0 > N1) ? N0 : N1;

    // ---- carve workspace ----
    char* p = (char*)d_ws;
    auto alloc = [&](size_t bytes) -> void* {
        void* r = (void*)p;
        p += (bytes + 255) & ~(size_t)255;
        return r;
    };
    unsigned short* h[2];
    unsigned short* q[2];
    float* agg[2];
    h[0] = (unsigned short*)alloc((size_t)N0 * 128 * 2);
    h[1] = (unsigned short*)alloc((size_t)N1 * 128 * 2);
    q[0] = (unsigned short*)alloc((size_t)N0 * 128 * 2);
    q[1] = (unsigned short*)alloc((size_t)N1 * 128 * 2);
    agg[0] = (float*)alloc((size_t)N0 * 128 * 4);
    agg[1] = (float*)alloc((size_t)N1 * 128 * 4);
    unsigned short* kr = (unsigned short*)alloc((size_t)Nmax * 128 * 2);
    unsigned short* vr = (unsigned short*)alloc((size_t)Nmax * 128 * 2);
    int* indptr[3];
    int* ssrc[3];
    int Er[3];
    for (int r = 0; r < 3; ++r) {
        Er[r] = in_sizes[2 + r] / 2;
        indptr[r] = (int*)alloc((size_t)(Ns[RD[r]] + 1) * 4);
        ssrc[r] = (int*)alloc((size_t)Er[r] * 4);
    }
    int* cnt = (int*)alloc((size_t)Nmax * 4);  // also cursor
    int* texcl = (int*)alloc((size_t)Nmax * 4);
    int* bsums = (int*)alloc(256 * 4);
    unsigned short* winT = (unsigned short*)alloc(2 * 8192 * 2);
    unsigned short* wqT = (unsigned short*)alloc((size_t)L * 2 * 16384 * 2);
    unsigned short* waT = (unsigned short*)alloc((size_t)L * 2 * 16384 * 2);
    unsigned short* wfT = (unsigned short*)alloc((size_t)L * 6 * 16384 * 2);
    float* bfold = (float*)alloc((size_t)L * 6 * 128 * 4);
    float* gsum = (float*)alloc(128 * 4);

    // ---- weight prep (once) ----
    {
        int nmat = L * 2;
        int convN = 2 * 8192 + 2 * nmat * 16384;
        convT_kernel<<<(convN + 255) / 256, 256, 0, stream>>>(Win[0], Win[1], Wq, Wa, winT, wqT,
                                                              waT, nmat);
        int foldN = L * 6 * 16384 + L * 6 * 128;
        fold_kernel<<<(foldN + 255) / 256, 256, 0, stream>>>(Wk, bk, Wv, bv, a_rel, m_rel, wfT,
                                                             bfold, L);
    }

    // ---- CSR build (once; reused across layers) ----
    for (int r = 0; r < 3; ++r) {
        int Nd = Ns[RD[r]];
        int E = Er[r];
        int nb = (Nd + 1023) / 1024;
        hipMemsetAsync(cnt, 0, (size_t)Nd * 4, stream);
        hist_kernel<<<(E + 255) / 256, 256, 0, stream>>>(edges[r] + E, cnt, E);
        scanA_kernel<<<nb, 1024, 0, stream>>>(cnt, texcl, bsums, Nd);
        scanB_kernel<<<1, 64, 0, stream>>>(bsums, nb);
        scanC_kernel<<<nb, 1024, 0, stream>>>(texcl, bsums, indptr[r], cnt, Nd, E);
        scatter_kernel<<<(E + 255) / 256, 256, 0, stream>>>(edges[r], edges[r] + E, cnt, ssrc[r],
                                                            E);
    }

    // ---- input projection: h[t] = relu(x @ Win + bin), bf16 out ----
    for (int t = 0; t < 2; ++t) {
        gemm_mfma<64, 1, 1><<<(Ns[t] + 127) / 128, 256, 0, stream>>>(
            x[t], winT + t * 8192, bin[t], h[t], Ns[t], nullptr, nullptr);
    }

    // ---- layers ----
    for (int l = 0; l < L; ++l) {
        for (int t = 0; t < 2; ++t) {
            gemm_mfma<128, 0, 0><<<(Ns[t] + 127) / 128, 256, 0, stream>>>(
                h[t], wqT + (size_t)(l * 2 + t) * 16384, bq + (size_t)(l * 2 + t) * 128, q[t],
                Ns[t], nullptr, nullptr);
        }
        for (int r = 0; r < 3; ++r) {
            int s = RS[r], d = RD[r];
            int fk = (l * 3 + r) * 2, fv = fk + 1;
            gemm_mfma<128, 0, 0><<<(Ns[s] + 127) / 128, 256, 0, stream>>>(
                h[s], wfT + (size_t)fk * 16384, bfold + (size_t)fk * 128, kr, Ns[s], nullptr,
                nullptr);
            gemm_mfma<128, 0, 0><<<(Ns[s] + 127) / 128, 256, 0, stream>>>(
                h[s], wfT + (size_t)fv * 16384, bfold + (size_t)fv * 128, vr, Ns[s], nullptr,
                nullptr);
            int Nd = Ns[d];
            dim3 grid((Nd + 3) / 4);
            const float* p_lr = p_rel + (size_t)(l * 3 + r) * 8;
            if (r == 1)
                attn_kernel<1><<<grid, 256, 0, stream>>>(q[d], kr, vr, indptr[r], ssrc[r], agg[d],
                                                         p_lr, Nd);
            else
                attn_kernel<0><<<grid, 256, 0, stream>>>(q[d], kr, vr, indptr[r], ssrc[r], agg[d],
                                                         p_lr, Nd);
        }
        for (int t = 0; t < 2; ++t) {
            gemm_mfma<128, 2, 1><<<(Ns[t] + 127) / 128, 256, 0, stream>>>(
                agg[t], waT + (size_t)(l * 2 + t) * 16384, ba + (size_t)(l * 2 + t) * 128, h[t],
                Ns[t], h[t], skip + (size_t)(l * 2 + t));
        }
    }

    // ---- readout ----
    hipMemsetAsync(gsum, 0, 128 * 4, stream);
    colsum_kernel<<<512, 128, 0, stream>>>(h[0], gsum, N0);
    final_kernel<<<1, 128, 0, stream>>>(gsum, Wc1, bc1, Wc2, bc2, (float*)d_out,
                                        1.0f / (float)N0);
}

// Round 3
// 974.171 us; speedup vs baseline: 1.7555x; 1.0257x over previous
//
#include <hip/hip_runtime.h>
#include <hip/hip_fp8.h>
#include <math.h>

typedef __attribute__((ext_vector_type(8))) short short8v;   // 8 x bf16 (4 VGPRs)
typedef __attribute__((ext_vector_type(4))) float f32x4;

__device__ __forceinline__ float bf2f(unsigned short u) {
    union { unsigned int i; float f; } x; x.i = ((unsigned int)u) << 16; return x.f;
}
__device__ __forceinline__ unsigned short f2bf(float f) {
    union { float f; unsigned int i; } x; x.f = f;
    unsigned int r = x.i + 0x7fffu + ((x.i >> 16) & 1u);
    return (unsigned short)(r >> 16);
}
__device__ __forceinline__ unsigned char f2fp8(float f) {
    __hip_fp8_e4m3 t(f);
    return (unsigned char)t.__x;
}
__device__ __forceinline__ float fp8tof(unsigned int b) {
    __hip_fp8_e4m3 t;
    t.__x = (__hip_fp8_storage_t)(b & 0xffu);
    return (float)t;
}
__device__ __forceinline__ float gelu_exact(float x) {
    return 0.5f * x * (1.0f + erff(x * 0.70710678118654752f));
}

// ============ bf16 MFMA GEMM (input/output projections) ============
// C[M x 128] = act(A[M x K] @ B + bias); B passed as BT bf16 [128][K]. Output bf16.
// MODE 1: relu; MODE 2: gelu on A-load + skip blend epilogue. ASRC 1: A fp32.
template <int K, int MODE, int ASRC>
__global__ __launch_bounds__(256) void gemm_mfma(
    const void* __restrict__ Aptr, const unsigned short* __restrict__ BT,
    const float* __restrict__ bias, unsigned short* __restrict__ Cout, int M,
    const unsigned short* __restrict__ hprev, const float* __restrict__ skipp) {
    __shared__ short As[128 * K];
    __shared__ short Bs[128 * K];
    const int tid = threadIdx.x;
    const int row0 = blockIdx.x * 128;
    const int CH = K / 8;

#pragma unroll
    for (int i = 0; i < (128 * CH) / 256; ++i) {
        int idx = tid + i * 256;
        int r = idx / CH, c = idx % CH;
        int gr = row0 + r;
        short8v val = {0, 0, 0, 0, 0, 0, 0, 0};
        if (gr < M) {
            if (ASRC == 0) {
                val = *reinterpret_cast<const short8v*>(
                    (const unsigned short*)Aptr + (size_t)gr * K + c * 8);
            } else {
                const float* Af = (const float*)Aptr;
                float4 f0 = *reinterpret_cast<const float4*>(Af + (size_t)gr * K + c * 8);
                float4 f1 = *reinterpret_cast<const float4*>(Af + (size_t)gr * K + c * 8 + 4);
                float fa[8] = {f0.x, f0.y, f0.z, f0.w, f1.x, f1.y, f1.z, f1.w};
#pragma unroll
                for (int u = 0; u < 8; ++u) {
                    float fv = fa[u];
                    if (MODE == 2) fv = gelu_exact(fv);
                    val[u] = (short)f2bf(fv);
                }
            }
        }
        *reinterpret_cast<short8v*>((char*)As + r * (2 * K) + ((c * 16) ^ ((r & 7) << 4))) = val;
    }
#pragma unroll
    for (int i = 0; i < (128 * CH) / 256; ++i) {
        int idx = tid + i * 256;
        int r = idx / CH, c = idx % CH;
        short8v val = *reinterpret_cast<const short8v*>(BT + (size_t)r * K + c * 8);
        *reinterpret_cast<short8v*>((char*)Bs + r * (2 * K) + ((c * 16) ^ ((r & 7) << 4))) = val;
    }
    __syncthreads();

    const int lane = tid & 63, wid = tid >> 6;
    const int wr = wid >> 1, wc = wid & 1;
    const int lr = lane & 15, lg = lane >> 4;
    const int swz = (lr & 7) << 4;
    f32x4 acc[4][4];
    f32x4 z4 = {0.f, 0.f, 0.f, 0.f};
#pragma unroll
    for (int mi = 0; mi < 4; ++mi)
#pragma unroll
        for (int ni = 0; ni < 4; ++ni) acc[mi][ni] = z4;

#pragma unroll
    for (int ks = 0; ks < K / 32; ++ks) {
        int kc = ks * 64 + lg * 16;
        short8v a[4], b[4];
#pragma unroll
        for (int mi = 0; mi < 4; ++mi) {
            int r = wr * 64 + mi * 16 + lr;
            a[mi] = *reinterpret_cast<const short8v*>((char*)As + r * (2 * K) + (kc ^ swz));
        }
#pragma unroll
        for (int ni = 0; ni < 4; ++ni) {
            int r = wc * 64 + ni * 16 + lr;
            b[ni] = *reinterpret_cast<const short8v*>((char*)Bs + r * (2 * K) + (kc ^ swz));
        }
#pragma unroll
        for (int mi = 0; mi < 4; ++mi)
#pragma unroll
            for (int ni = 0; ni < 4; ++ni)
                acc[mi][ni] =
                    __builtin_amdgcn_mfma_f32_16x16x32_bf16(a[mi], b[ni], acc[mi][ni], 0, 0, 0);
    }

    float beta = 0.f;
    if (MODE == 2) beta = 1.f / (1.f + expf(-skipp[0]));
#pragma unroll
    for (int mi = 0; mi < 4; ++mi) {
#pragma unroll
        for (int ni = 0; ni < 4; ++ni) {
            int col = wc * 64 + ni * 16 + lr;
            float bv = bias[col];
#pragma unroll
            for (int j = 0; j < 4; ++j) {
                int gr = row0 + wr * 64 + mi * 16 + lg * 4 + j;
                if (gr < M) {
                    float v = acc[mi][ni][j] + bv;
                    if (MODE == 1) v = fmaxf(v, 0.f);
                    if (MODE == 2) v = beta * v + (1.f - beta) * bf2f(hprev[(size_t)gr * 128 + col]);
                    Cout[(size_t)gr * 128 + col] = f2bf(v);
                }
            }
        }
    }
}

// ============ fused QKV GEMM: one A-tile, NB B-matrices ============
// Job m: out bf16 [M][128] if outBf != null, else fp8 bytes into outF8 (row
// stride 256, byte offset f8off).
struct QKVJobs {
    const unsigned short* BT[5];
    const float* bias[5];
    unsigned short* outBf[5];
    unsigned char* outF8[5];
    int f8off[5];
};

template <int NB>
__global__ __launch_bounds__(256) void gemm_qkv(const unsigned short* __restrict__ A,
                                                QKVJobs J, int M) {
    __shared__ short As[128 * 128];
    __shared__ short Bs[128 * 128];
    const int tid = threadIdx.x;
    const int row0 = blockIdx.x * 128;

#pragma unroll
    for (int i = 0; i < 8; ++i) {
        int idx = tid + i * 256;
        int r = idx >> 4, c = idx & 15;
        int gr = row0 + r;
        short8v val = {0, 0, 0, 0, 0, 0, 0, 0};
        if (gr < M) val = *reinterpret_cast<const short8v*>(A + (size_t)gr * 128 + c * 8);
        *reinterpret_cast<short8v*>((char*)As + r * 256 + ((c * 16) ^ ((r & 7) << 4))) = val;
    }

    const int lane = tid & 63, wid = tid >> 6;
    const int wr = wid >> 1, wc = wid & 1;
    const int lr = lane & 15, lg = lane >> 4;
    const int swz = (lr & 7) << 4;

#pragma unroll
    for (int m = 0; m < NB; ++m) {
        const unsigned short* BT = J.BT[m];
#pragma unroll
        for (int i = 0; i < 8; ++i) {
            int idx = tid + i * 256;
            int r = idx >> 4, c = idx & 15;
            short8v val = *reinterpret_cast<const short8v*>(BT + (size_t)r * 128 + c * 8);
            *reinterpret_cast<short8v*>((char*)Bs + r * 256 + ((c * 16) ^ ((r & 7) << 4))) = val;
        }
        __syncthreads();

        f32x4 acc[4][4];
        f32x4 z4 = {0.f, 0.f, 0.f, 0.f};
#pragma unroll
        for (int mi = 0; mi < 4; ++mi)
#pragma unroll
            for (int ni = 0; ni < 4; ++ni) acc[mi][ni] = z4;

#pragma unroll
        for (int ks = 0; ks < 4; ++ks) {
            int kc = ks * 64 + lg * 16;
            short8v a[4], b[4];
#pragma unroll
            for (int mi = 0; mi < 4; ++mi) {
                int r = wr * 64 + mi * 16 + lr;
                a[mi] = *reinterpret_cast<const short8v*>((char*)As + r * 256 + (kc ^ swz));
            }
#pragma unroll
            for (int ni = 0; ni < 4; ++ni) {
                int r = wc * 64 + ni * 16 + lr;
                b[ni] = *reinterpret_cast<const short8v*>((char*)Bs + r * 256 + (kc ^ swz));
            }
#pragma unroll
            for (int mi = 0; mi < 4; ++mi)
#pragma unroll
                for (int ni = 0; ni < 4; ++ni)
                    acc[mi][ni] = __builtin_amdgcn_mfma_f32_16x16x32_bf16(a[mi], b[ni],
                                                                          acc[mi][ni], 0, 0, 0);
        }

        unsigned short* outBf = J.outBf[m];
        unsigned char* outF8 = J.outF8[m];
        int off = J.f8off[m];
        const float* bias = J.bias[m];
#pragma unroll
        for (int mi = 0; mi < 4; ++mi) {
#pragma unroll
            for (int ni = 0; ni < 4; ++ni) {
                int col = wc * 64 + ni * 16 + lr;
                float bv = bias[col];
#pragma unroll
                for (int j = 0; j < 4; ++j) {
                    int gr = row0 + wr * 64 + mi * 16 + lg * 4 + j;
                    if (gr < M) {
                        float v = acc[mi][ni][j] + bv;
                        if (outBf) outBf[(size_t)gr * 128 + col] = f2bf(v);
                        else outF8[(size_t)gr * 256 + off + col] = f2fp8(v);
                    }
                }
            }
        }
        __syncthreads();
    }
}

// ============ weight prep: transpose + bf16 convert ============
__global__ void convT_kernel(const float* __restrict__ Win0, const float* __restrict__ Win1,
                             const float* __restrict__ Wq, const float* __restrict__ Wa,
                             unsigned short* __restrict__ winT, unsigned short* __restrict__ wqT,
                             unsigned short* __restrict__ waT, int nmat) {
    int gid = blockIdx.x * 256 + threadIdx.x;
    if (gid < 2 * 8192) {
        int m = gid >> 13, idx = gid & 8191;
        int n = idx >> 6, k = idx & 63;
        const float* W = m ? Win1 : Win0;
        winT[gid] = f2bf(W[(size_t)k * 128 + n]);
        return;
    }
    int g = gid - 2 * 8192;
    if (g < nmat * 16384) {
        int mat = g >> 14, idx = g & 16383;
        int n = idx >> 7, k = idx & 127;
        wqT[g] = f2bf(Wq[(size_t)mat * 16384 + (size_t)k * 128 + n]);
        return;
    }
    g -= nmat * 16384;
    if (g < nmat * 16384) {
        int mat = g >> 14, idx = g & 16383;
        int n = idx >> 7, k = idx & 127;
        waT[g] = f2bf(Wa[(size_t)mat * 16384 + (size_t)k * 128 + n]);
    }
}

// ============ relation fold ============
__global__ void fold_kernel(const float* __restrict__ Wk, const float* __restrict__ bk,
                            const float* __restrict__ Wv, const float* __restrict__ bv,
                            const float* __restrict__ a_rel, const float* __restrict__ m_rel,
                            unsigned short* __restrict__ wfT, float* __restrict__ bfold, int L) {
    const int RSarr[3] = {0, 1, 0};
    int gid = blockIdx.x * 256 + threadIdx.x;
    int NW = L * 6 * 16384;
    if (gid < NW) {
        int fold = gid >> 14, idx = gid & 16383;
        int col = idx >> 7, i = idx & 127;
        int kv = fold & 1, lr = fold >> 1, l = lr / 3, r = lr % 3;
        int s = RSarr[r];
        const float* W = (kv ? Wv : Wk) + (size_t)(l * 2 + s) * 16384;
        const float* rel = (kv ? m_rel : a_rel) + (size_t)(l * 3 + r) * 2048;
        int hh = col >> 4, f = col & 15;
        float sacc = 0.f;
#pragma unroll
        for (int d = 0; d < 16; ++d)
            sacc += W[(size_t)i * 128 + hh * 16 + d] * rel[hh * 256 + d * 16 + f];
        wfT[gid] = f2bf(sacc);
        return;
    }
    int g = gid - NW;
    if (g >= L * 6 * 128) return;
    int fold = g >> 7, col = g & 127;
    int kv = fold & 1, lr = fold >> 1, l = lr / 3, r = lr % 3;
    int s = RSarr[r];
    const float* b = (kv ? bv : bk) + (size_t)(l * 2 + s) * 128;
    const float* rel = (kv ? m_rel : a_rel) + (size_t)(l * 3 + r) * 2048;
    int hh = col >> 4, f = col & 15;
    float sacc = 0.f;
#pragma unroll
    for (int d = 0; d < 16; ++d) sacc += b[hh * 16 + d] * rel[hh * 256 + d * 16 + f];
    bfold[fold * 128 + col] = sacc;
}

// ============ CSR build ============
__global__ void hist_kernel(const int* __restrict__ dst, int* __restrict__ cnt, int E) {
    int e = blockIdx.x * 256 + threadIdx.x;
    if (e < E) atomicAdd(&cnt[dst[e]], 1);
}

__global__ __launch_bounds__(1024) void scanA_kernel(const int* __restrict__ cnt,
                                                     int* __restrict__ texcl,
                                                     int* __restrict__ bsums, int n) {
    __shared__ int s[1024];
    int t = threadIdx.x;
    int gid = blockIdx.x * 1024 + t;
    int x = (gid < n) ? cnt[gid] : 0;
    s[t] = x;
    __syncthreads();
    for (int off = 1; off < 1024; off <<= 1) {
        int v = (t >= off) ? s[t - off] : 0;
        __syncthreads();
        s[t] += v;
        __syncthreads();
    }
    if (gid < n) texcl[gid] = s[t] - x;
    if (t == 1023) bsums[blockIdx.x] = s[1023];
}

__global__ void scanB_kernel(int* bsums, int nb) {
    if (threadIdx.x == 0 && blockIdx.x == 0) {
        int run = 0;
        for (int i = 0; i < nb; ++i) { int t = bsums[i]; bsums[i] = run; run += t; }
    }
}

__global__ __launch_bounds__(1024) void scanC_kernel(const int* __restrict__ texcl,
                                                     const int* __restrict__ bsums,
                                                     int* __restrict__ indptr,
                                                     int* __restrict__ cursor, int n, int E) {
    int gid = blockIdx.x * 1024 + threadIdx.x;
    if (gid < n) {
        int v = texcl[gid] + bsums[blockIdx.x];
        indptr[gid] = v;
        cursor[gid] = v;
    }
    if (gid == 0) indptr[n] = E;
}

__global__ void scatter_kernel(const int* __restrict__ src, const int* __restrict__ dst,
                               int* __restrict__ cursor, int* __restrict__ ssrc, int E) {
    int e = blockIdx.x * 256 + threadIdx.x;
    if (e < E) {
        int p = atomicAdd(&cursor[dst[e]], 1);
        ssrc[p] = src[e];
    }
}

// ============ attention: fp8 interleaved kv, one wave per dst ============
// kv[src] is 256 B: bytes 0..127 = K cols (fp8 e4m3), 128..255 = V cols.
// Lanes 0..31 handle K (4 cols each), lanes 32..63 handle V (4 cols each).
template <int ACC>
__global__ __launch_bounds__(256) void attn_kernel(
    const unsigned short* __restrict__ qd, const unsigned char* __restrict__ kv,
    const int* __restrict__ indptr, const int* __restrict__ ssrc,
    float* __restrict__ agg, const float* __restrict__ prel, int Nd) {
    int wave = (blockIdx.x * blockDim.x + threadIdx.x) >> 6;
    int lane = threadIdx.x & 63;
    if (wave >= Nd) return;
    const int lq = lane & 31;
    const int head = lq >> 2;
    const bool isV = lane >= 32;
    const float p = prel[head] * 0.25f;  // * 1/sqrt(D)
    float qf[4];
    {
        ushort4 qv = *reinterpret_cast<const ushort4*>(qd + (size_t)wave * 128 + lq * 4);
        qf[0] = bf2f(qv.x); qf[1] = bf2f(qv.y); qf[2] = bf2f(qv.z); qf[3] = bf2f(qv.w);
    }
    int beg = indptr[wave], end = indptr[wave + 1];
    float m = -INFINITY, ssum = 0.f;
    float a0 = 0.f, a1 = 0.f, a2 = 0.f, a3 = 0.f;
    unsigned int cur = 0;
    if (beg < end) {
        int s0 = ssrc[beg];
        cur = *reinterpret_cast<const unsigned int*>(kv + (size_t)s0 * 256 + lane * 4);
    }
    for (int i = beg; i < end; ++i) {
        unsigned int nxt = 0;
        if (i + 1 < end) {
            int s1 = ssrc[i + 1];
            nxt = *reinterpret_cast<const unsigned int*>(kv + (size_t)s1 * 256 + lane * 4);
        }
        float f0 = fp8tof(cur), f1 = fp8tof(cur >> 8), f2 = fp8tof(cur >> 16),
              f3 = fp8tof(cur >> 24);
        float t = qf[0] * f0 + qf[1] * f1 + qf[2] * f2 + qf[3] * f3;
        t += __shfl_xor(t, 1);
        t += __shfl_xor(t, 2);
        float tc = __shfl_xor(t, 32);
        if (isV) t = tc;
        float alpha = t * p;
        float nm = fmaxf(m, alpha);
        float sc = __expf(m - nm);
        float w = __expf(alpha - nm);
        ssum = ssum * sc + w;
        a0 = a0 * sc + w * f0;
        a1 = a1 * sc + w * f1;
        a2 = a2 * sc + w * f2;
        a3 = a3 * sc + w * f3;
        m = nm;
        cur = nxt;
    }
    if (isV) {
        float inv = 1.f / fmaxf(ssum, 1e-16f);
        float4* dp = reinterpret_cast<float4*>(agg + (size_t)wave * 128 + (lane - 32) * 4);
        float4 r = make_float4(a0 * inv, a1 * inv, a2 * inv, a3 * inv);
        if (ACC) {
            float4 o = *dp;
            r.x += o.x; r.y += o.y; r.z += o.z; r.w += o.w;
        }
        *dp = r;
    }
}

// ============ readout ============
__global__ void colsum_kernel(const unsigned short* __restrict__ h, float* __restrict__ gsum,
                              int M) {
    int c = threadIdx.x;
    float s = 0.f;
    for (int r = blockIdx.x; r < M; r += gridDim.x) s += bf2f(h[(size_t)r * 128 + c]);
    atomicAdd(&gsum[c], s);
}

__global__ void final_kernel(const float* __restrict__ gsum, const float* __restrict__ Wc1,
                             const float* __restrict__ bc1, const float* __restrict__ Wc2,
                             const float* __restrict__ bc2, float* __restrict__ out,
                             float invM) {
    __shared__ float g[128];
    __shared__ float red[128];
    int t = threadIdx.x;
    g[t] = gsum[t] * invM;
    __syncthreads();
    float acc = bc1[t];
    for (int k = 0; k < 128; ++k) acc += g[k] * Wc1[k * 128 + t];
    float zv = fmaxf(acc, 0.f);
    red[t] = zv * Wc2[t];
    __syncthreads();
    for (int off = 64; off > 0; off >>= 1) {
        if (t < off) red[t] += red[t + off];
        __syncthreads();
    }
    if (t == 0) out[0] = 1.f / (1.f + expf(-(red[0] + bc2[0])));
}

extern "C" void kernel_launch(void* const* d_in, const int* in_sizes, int n_in,
                              void* d_out, int out_size, void* d_ws, size_t ws_size,
                              hipStream_t stream) {
    const float* x[2] = {(const float*)d_in[0], (const float*)d_in[1]};
    const int* edges[3] = {(const int*)d_in[2], (const int*)d_in[3], (const int*)d_in[4]};
    const float* Win[2] = {(const float*)d_in[5], (const float*)d_in[7]};
    const float* bin[2] = {(const float*)d_in[6], (const float*)d_in[8]};
    const float* Wk = (const float*)d_in[9];
    const float* bk = (const float*)d_in[10];
    const float* Wq = (const float*)d_in[11];
    const float* bq = (const float*)d_in[12];
    const float* Wv = (const float*)d_in[13];
    const float* bv = (const float*)d_in[14];
    const float* a_rel = (const float*)d_in[15];
    const float* m_rel = (const float*)d_in[16];
    const float* p_rel = (const float*)d_in[17];
    const float* Wa = (const float*)d_in[18];
    const float* ba = (const float*)d_in[19];
    const float* skip = (const float*)d_in[20];
    const float* Wc1 = (const float*)d_in[21];
    const float* bc1 = (const float*)d_in[22];
    const float* Wc2 = (const float*)d_in[23];
    const float* bc2 = (const float*)d_in[24];

    const int N0 = in_sizes[0] / 64;
    const int N1 = in_sizes[1] / 64;
    const int L = in_sizes[9] / (2 * 128 * 128);
    const int Ns[2] = {N0, N1};
    const int RD[3] = {0, 0, 1};
    const int Nmax = (N0 > N1) ? N0 : N1;

    char* p = (char*)d_ws;
    auto alloc = [&](size_t bytes) -> void* {
        void* r = (void*)p;
        p += (bytes + 255) & ~(size_t)255;
        return r;
    };
    unsigned short* h[2];
    unsigned short* q[2];
    float* agg[2];
    h[0] = (unsigned short*)alloc((size_t)N0 * 128 * 2);
    h[1] = (unsigned short*)alloc((size_t)N1 * 128 * 2);
    q[0] = (unsigned short*)alloc((size_t)N0 * 128 * 2);
    q[1] = (unsigned short*)alloc((size_t)N1 * 128 * 2);
    agg[0] = (float*)alloc((size_t)N0 * 128 * 4);
    agg[1] = (float*)alloc((size_t)N1 * 128 * 4);
    unsigned char* kv8[3];
    for (int r = 0; r < 3; ++r) kv8[r] = (unsigned char*)alloc((size_t)Nmax * 256);
    int* indptr[3];
    int* ssrc[3];
    int Er[3];
    for (int r = 0; r < 3; ++r) {
        Er[r] = in_sizes[2 + r] / 2;
        indptr[r] = (int*)alloc((size_t)(Ns[RD[r]] + 1) * 4);
        ssrc[r] = (int*)alloc((size_t)Er[r] * 4);
    }
    int* cnt = (int*)alloc((size_t)Nmax * 4);
    int* texcl = (int*)alloc((size_t)Nmax * 4);
    int* bsums = (int*)alloc(256 * 4);
    unsigned short* winT = (unsigned short*)alloc(2 * 8192 * 2);
    unsigned short* wqT = (unsigned short*)alloc((size_t)L * 2 * 16384 * 2);
    unsigned short* waT = (unsigned short*)alloc((size_t)L * 2 * 16384 * 2);
    unsigned short* wfT = (unsigned short*)alloc((size_t)L * 6 * 16384 * 2);
    float* bfold = (float*)alloc((size_t)L * 6 * 128 * 4);
    float* gsum = (float*)alloc(128 * 4);

    // ---- weight prep ----
    {
        int nmat = L * 2;
        int convN = 2 * 8192 + 2 * nmat * 16384;
        convT_kernel<<<(convN + 255) / 256, 256, 0, stream>>>(Win[0], Win[1], Wq, Wa, winT, wqT,
                                                              waT, nmat);
        int foldN = L * 6 * 16384 + L * 6 * 128;
        fold_kernel<<<(foldN + 255) / 256, 256, 0, stream>>>(Wk, bk, Wv, bv, a_rel, m_rel, wfT,
                                                             bfold, L);
    }

    // ---- CSR build ----
    for (int r = 0; r < 3; ++r) {
        int Nd = Ns[RD[r]];
        int E = Er[r];
        int nb = (Nd + 1023) / 1024;
        hipMemsetAsync(cnt, 0, (size_t)Nd * 4, stream);
        hist_kernel<<<(E + 255) / 256, 256, 0, stream>>>(edges[r] + E, cnt, E);
        scanA_kernel<<<nb, 1024, 0, stream>>>(cnt, texcl, bsums, Nd);
        scanB_kernel<<<1, 64, 0, stream>>>(bsums, nb);
        scanC_kernel<<<nb, 1024, 0, stream>>>(texcl, bsums, indptr[r], cnt, Nd, E);
        scatter_kernel<<<(E + 255) / 256, 256, 0, stream>>>(edges[r], edges[r] + E, cnt, ssrc[r],
                                                            E);
    }

    // ---- input projection ----
    for (int t = 0; t < 2; ++t) {
        gemm_mfma<64, 1, 1><<<(Ns[t] + 127) / 128, 256, 0, stream>>>(
            x[t], winT + t * 8192, bin[t], h[t], Ns[t], nullptr, nullptr);
    }

    // ---- layers ----
    for (int l = 0; l < L; ++l) {
        // fused QKV: type 0 sources relations r0 (d=0) and r2 (d=1); type 1 sources r1.
        {
            QKVJobs J{};
            J.BT[0] = wqT + (size_t)(l * 2 + 0) * 16384;
            J.bias[0] = bq + (size_t)(l * 2 + 0) * 128;
            J.outBf[0] = q[0]; J.outF8[0] = nullptr; J.f8off[0] = 0;
            int fk0 = (l * 3 + 0) * 2, fk2 = (l * 3 + 2) * 2;
            J.BT[1] = wfT + (size_t)fk0 * 16384;       J.bias[1] = bfold + (size_t)fk0 * 128;
            J.outBf[1] = nullptr; J.outF8[1] = kv8[0]; J.f8off[1] = 0;
            J.BT[2] = wfT + (size_t)(fk0 + 1) * 16384; J.bias[2] = bfold + (size_t)(fk0 + 1) * 128;
            J.outBf[2] = nullptr; J.outF8[2] = kv8[0]; J.f8off[2] = 128;
            J.BT[3] = wfT + (size_t)fk2 * 16384;       J.bias[3] = bfold + (size_t)fk2 * 128;
            J.outBf[3] = nullptr; J.outF8[3] = kv8[2]; J.f8off[3] = 0;
            J.BT[4] = wfT + (size_t)(fk2 + 1) * 16384; J.bias[4] = bfold + (size_t)(fk2 + 1) * 128;
            J.outBf[4] = nullptr; J.outF8[4] = kv8[2]; J.f8off[4] = 128;
            gemm_qkv<5><<<(N0 + 127) / 128, 256, 0, stream>>>(h[0], J, N0);
        }
        {
            QKVJobs J{};
            J.BT[0] = wqT + (size_t)(l * 2 + 1) * 16384;
            J.bias[0] = bq + (size_t)(l * 2 + 1) * 128;
            J.outBf[0] = q[1]; J.outF8[0] = nullptr; J.f8off[0] = 0;
            int fk1 = (l * 3 + 1) * 2;
            J.BT[1] = wfT + (size_t)fk1 * 16384;       J.bias[1] = bfold + (size_t)fk1 * 128;
            J.outBf[1] = nullptr; J.outF8[1] = kv8[1]; J.f8off[1] = 0;
            J.BT[2] = wfT + (size_t)(fk1 + 1) * 16384; J.bias[2] = bfold + (size_t)(fk1 + 1) * 128;
            J.outBf[2] = nullptr; J.outF8[2] = kv8[1]; J.f8off[2] = 128;
            gemm_qkv<3><<<(N1 + 127) / 128, 256, 0, stream>>>(h[1], J, N1);
        }
        // attention per relation
        for (int r = 0; r < 3; ++r) {
            int d = RD[r];
            int Nd = Ns[d];
            dim3 grid((Nd + 3) / 4);
            const float* p_lr = p_rel + (size_t)(l * 3 + r) * 8;
            if (r == 1)
                attn_kernel<1><<<grid, 256, 0, stream>>>(q[d], kv8[r], indptr[r], ssrc[r], agg[d],
                                                         p_lr, Nd);
            else
                attn_kernel<0><<<grid, 256, 0, stream>>>(q[d], kv8[r], indptr[r], ssrc[r], agg[d],
                                                         p_lr, Nd);
        }
        // output projection + skip
        for (int t = 0; t < 2; ++t) {
            gemm_mfma<128, 2, 1><<<(Ns[t] + 127) / 128, 256, 0, stream>>>(
                agg[t], waT + (size_t)(l * 2 + t) * 16384, ba + (size_t)(l * 2 + t) * 128, h[t],
                Ns[t], h[t], skip + (size_t)(l * 2 + t));
        }
    }

    // ---- readout ----
    hipMemsetAsync(gsum, 0, 128 * 4, stream);
    colsum_kernel<<<512, 128, 0, stream>>>(h[0], gsum, N0);
    final_kernel<<<1, 128, 0, stream>>>(gsum, Wc1, bc1, Wc2, bc2, (float*)d_out,
                                        1.0f / (float)N0);
}

// Round 4
// 829.219 us; speedup vs baseline: 2.0624x; 1.1748x over previous
//
#include <hip/hip_runtime.h>
#include <hip/hip_fp8.h>
#include <math.h>

typedef __attribute__((ext_vector_type(8))) short short8v;   // 8 x bf16 (4 VGPRs)
typedef __attribute__((ext_vector_type(4))) float f32x4;
typedef __attribute__((ext_vector_type(2))) float f32x2;

__device__ __forceinline__ float bf2f(unsigned short u) {
    union { unsigned int i; float f; } x; x.i = ((unsigned int)u) << 16; return x.f;
}
__device__ __forceinline__ unsigned short f2bf(float f) {
    union { float f; unsigned int i; } x; x.f = f;
    unsigned int r = x.i + 0x7fffu + ((x.i >> 16) & 1u);
    return (unsigned short)(r >> 16);
}
__device__ __forceinline__ unsigned char f2fp8(float f) {
    __hip_fp8_e4m3 t(f);
    return (unsigned char)t.__x;
}
__device__ __forceinline__ float gelu_exact(float x) {
    return 0.5f * x * (1.0f + erff(x * 0.70710678118654752f));
}

// ============ bf16 MFMA GEMM (input/output projections) ============
template <int K, int MODE, int ASRC>
__global__ __launch_bounds__(256) void gemm_mfma(
    const void* __restrict__ Aptr, const unsigned short* __restrict__ BT,
    const float* __restrict__ bias, unsigned short* __restrict__ Cout, int M,
    const unsigned short* __restrict__ hprev, const float* __restrict__ skipp) {
    __shared__ short As[128 * K];
    __shared__ short Bs[128 * K];
    const int tid = threadIdx.x;
    const int row0 = blockIdx.x * 128;
    const int CH = K / 8;

#pragma unroll
    for (int i = 0; i < (128 * CH) / 256; ++i) {
        int idx = tid + i * 256;
        int r = idx / CH, c = idx % CH;
        int gr = row0 + r;
        short8v val = {0, 0, 0, 0, 0, 0, 0, 0};
        if (gr < M) {
            if (ASRC == 0) {
                val = *reinterpret_cast<const short8v*>(
                    (const unsigned short*)Aptr + (size_t)gr * K + c * 8);
            } else {
                const float* Af = (const float*)Aptr;
                float4 f0 = *reinterpret_cast<const float4*>(Af + (size_t)gr * K + c * 8);
                float4 f1 = *reinterpret_cast<const float4*>(Af + (size_t)gr * K + c * 8 + 4);
                float fa[8] = {f0.x, f0.y, f0.z, f0.w, f1.x, f1.y, f1.z, f1.w};
#pragma unroll
                for (int u = 0; u < 8; ++u) {
                    float fv = fa[u];
                    if (MODE == 2) fv = gelu_exact(fv);
                    val[u] = (short)f2bf(fv);
                }
            }
        }
        *reinterpret_cast<short8v*>((char*)As + r * (2 * K) + ((c * 16) ^ ((r & 7) << 4))) = val;
    }
#pragma unroll
    for (int i = 0; i < (128 * CH) / 256; ++i) {
        int idx = tid + i * 256;
        int r = idx / CH, c = idx % CH;
        short8v val = *reinterpret_cast<const short8v*>(BT + (size_t)r * K + c * 8);
        *reinterpret_cast<short8v*>((char*)Bs + r * (2 * K) + ((c * 16) ^ ((r & 7) << 4))) = val;
    }
    __syncthreads();

    const int lane = tid & 63, wid = tid >> 6;
    const int wr = wid >> 1, wc = wid & 1;
    const int lr = lane & 15, lg = lane >> 4;
    const int swz = (lr & 7) << 4;
    f32x4 acc[4][4];
    f32x4 z4 = {0.f, 0.f, 0.f, 0.f};
#pragma unroll
    for (int mi = 0; mi < 4; ++mi)
#pragma unroll
        for (int ni = 0; ni < 4; ++ni) acc[mi][ni] = z4;

#pragma unroll
    for (int ks = 0; ks < K / 32; ++ks) {
        int kc = ks * 64 + lg * 16;
        short8v a[4], b[4];
#pragma unroll
        for (int mi = 0; mi < 4; ++mi) {
            int r = wr * 64 + mi * 16 + lr;
            a[mi] = *reinterpret_cast<const short8v*>((char*)As + r * (2 * K) + (kc ^ swz));
        }
#pragma unroll
        for (int ni = 0; ni < 4; ++ni) {
            int r = wc * 64 + ni * 16 + lr;
            b[ni] = *reinterpret_cast<const short8v*>((char*)Bs + r * (2 * K) + (kc ^ swz));
        }
#pragma unroll
        for (int mi = 0; mi < 4; ++mi)
#pragma unroll
            for (int ni = 0; ni < 4; ++ni)
                acc[mi][ni] =
                    __builtin_amdgcn_mfma_f32_16x16x32_bf16(a[mi], b[ni], acc[mi][ni], 0, 0, 0);
    }

    float beta = 0.f;
    if (MODE == 2) beta = 1.f / (1.f + expf(-skipp[0]));
#pragma unroll
    for (int mi = 0; mi < 4; ++mi) {
#pragma unroll
        for (int ni = 0; ni < 4; ++ni) {
            int col = wc * 64 + ni * 16 + lr;
            float bv = bias[col];
#pragma unroll
            for (int j = 0; j < 4; ++j) {
                int gr = row0 + wr * 64 + mi * 16 + lg * 4 + j;
                if (gr < M) {
                    float v = acc[mi][ni][j] + bv;
                    if (MODE == 1) v = fmaxf(v, 0.f);
                    if (MODE == 2) v = beta * v + (1.f - beta) * bf2f(hprev[(size_t)gr * 128 + col]);
                    Cout[(size_t)gr * 128 + col] = f2bf(v);
                }
            }
        }
    }
}

// ============ fused QKV GEMM: one A-tile, NB B-matrices, B reg-prefetch ============
struct QKVJobs {
    const unsigned short* BT[5];
    const float* bias[5];
    unsigned short* outBf[5];
    unsigned char* outF8[5];
    int f8off[5];
};

template <int NB>
__global__ __launch_bounds__(256) void gemm_qkv(const unsigned short* __restrict__ A,
                                                QKVJobs J, int M) {
    __shared__ short As[128 * 128];
    __shared__ short Bs[128 * 128];
    const int tid = threadIdx.x;
    const int row0 = blockIdx.x * 128;

    short8v breg[8];
    // load B0 into regs
#pragma unroll
    for (int i = 0; i < 8; ++i) {
        int idx = tid + i * 256;
        int r = idx >> 4, c = idx & 15;
        breg[i] = *reinterpret_cast<const short8v*>(J.BT[0] + (size_t)r * 128 + c * 8);
    }
    // stage A
#pragma unroll
    for (int i = 0; i < 8; ++i) {
        int idx = tid + i * 256;
        int r = idx >> 4, c = idx & 15;
        int gr = row0 + r;
        short8v val = {0, 0, 0, 0, 0, 0, 0, 0};
        if (gr < M) val = *reinterpret_cast<const short8v*>(A + (size_t)gr * 128 + c * 8);
        *reinterpret_cast<short8v*>((char*)As + r * 256 + ((c * 16) ^ ((r & 7) << 4))) = val;
    }
    // write B0 to LDS
#pragma unroll
    for (int i = 0; i < 8; ++i) {
        int idx = tid + i * 256;
        int r = idx >> 4, c = idx & 15;
        *reinterpret_cast<short8v*>((char*)Bs + r * 256 + ((c * 16) ^ ((r & 7) << 4))) = breg[i];
    }

    const int lane = tid & 63, wid = tid >> 6;
    const int wr = wid >> 1, wc = wid & 1;
    const int lr = lane & 15, lg = lane >> 4;
    const int swz = (lr & 7) << 4;

#pragma unroll
    for (int m = 0; m < NB; ++m) {
        if (m + 1 < NB) {  // issue next-B loads (consumed after the next barrier)
#pragma unroll
            for (int i = 0; i < 8; ++i) {
                int idx = tid + i * 256;
                int r = idx >> 4, c = idx & 15;
                breg[i] = *reinterpret_cast<const short8v*>(J.BT[m + 1] + (size_t)r * 128 + c * 8);
            }
        }
        __syncthreads();  // Bs for job m visible to all

        f32x4 acc[4][4];
        f32x4 z4 = {0.f, 0.f, 0.f, 0.f};
#pragma unroll
        for (int mi = 0; mi < 4; ++mi)
#pragma unroll
            for (int ni = 0; ni < 4; ++ni) acc[mi][ni] = z4;

#pragma unroll
        for (int ks = 0; ks < 4; ++ks) {
            int kc = ks * 64 + lg * 16;
            short8v a[4], b[4];
#pragma unroll
            for (int mi = 0; mi < 4; ++mi) {
                int r = wr * 64 + mi * 16 + lr;
                a[mi] = *reinterpret_cast<const short8v*>((char*)As + r * 256 + (kc ^ swz));
            }
#pragma unroll
            for (int ni = 0; ni < 4; ++ni) {
                int r = wc * 64 + ni * 16 + lr;
                b[ni] = *reinterpret_cast<const short8v*>((char*)Bs + r * 256 + (kc ^ swz));
            }
#pragma unroll
            for (int mi = 0; mi < 4; ++mi)
#pragma unroll
                for (int ni = 0; ni < 4; ++ni)
                    acc[mi][ni] = __builtin_amdgcn_mfma_f32_16x16x32_bf16(a[mi], b[ni],
                                                                          acc[mi][ni], 0, 0, 0);
        }
        __syncthreads();  // all waves done reading Bs
        if (m + 1 < NB) {
#pragma unroll
            for (int i = 0; i < 8; ++i) {
                int idx = tid + i * 256;
                int r = idx >> 4, c = idx & 15;
                *reinterpret_cast<short8v*>((char*)Bs + r * 256 + ((c * 16) ^ ((r & 7) << 4))) =
                    breg[i];
            }
        }

        unsigned short* outBf = J.outBf[m];
        unsigned char* outF8 = J.outF8[m];
        int off = J.f8off[m];
        const float* bias = J.bias[m];
#pragma unroll
        for (int mi = 0; mi < 4; ++mi) {
#pragma unroll
            for (int ni = 0; ni < 4; ++ni) {
                int col = wc * 64 + ni * 16 + lr;
                float bv = bias[col];
#pragma unroll
                for (int j = 0; j < 4; ++j) {
                    int gr = row0 + wr * 64 + mi * 16 + lg * 4 + j;
                    if (gr < M) {
                        float v = acc[mi][ni][j] + bv;
                        if (outBf) outBf[(size_t)gr * 128 + col] = f2bf(v);
                        else outF8[(size_t)gr * 256 + off + col] = f2fp8(v);
                    }
                }
            }
        }
    }
}

// ============ weight prep ============
__global__ void convT_kernel(const float* __restrict__ Win0, const float* __restrict__ Win1,
                             const float* __restrict__ Wq, const float* __restrict__ Wa,
                             unsigned short* __restrict__ winT, unsigned short* __restrict__ wqT,
                             unsigned short* __restrict__ waT, int nmat) {
    int gid = blockIdx.x * 256 + threadIdx.x;
    if (gid < 2 * 8192) {
        int m = gid >> 13, idx = gid & 8191;
        int n = idx >> 6, k = idx & 63;
        const float* W = m ? Win1 : Win0;
        winT[gid] = f2bf(W[(size_t)k * 128 + n]);
        return;
    }
    int g = gid - 2 * 8192;
    if (g < nmat * 16384) {
        int mat = g >> 14, idx = g & 16383;
        int n = idx >> 7, k = idx & 127;
        wqT[g] = f2bf(Wq[(size_t)mat * 16384 + (size_t)k * 128 + n]);
        return;
    }
    g -= nmat * 16384;
    if (g < nmat * 16384) {
        int mat = g >> 14, idx = g & 16383;
        int n = idx >> 7, k = idx & 127;
        waT[g] = f2bf(Wa[(size_t)mat * 16384 + (size_t)k * 128 + n]);
    }
}

// ============ relation fold ============
__global__ void fold_kernel(const float* __restrict__ Wk, const float* __restrict__ bk,
                            const float* __restrict__ Wv, const float* __restrict__ bv,
                            const float* __restrict__ a_rel, const float* __restrict__ m_rel,
                            unsigned short* __restrict__ wfT, float* __restrict__ bfold, int L) {
    const int RSarr[3] = {0, 1, 0};
    int gid = blockIdx.x * 256 + threadIdx.x;
    int NW = L * 6 * 16384;
    if (gid < NW) {
        int fold = gid >> 14, idx = gid & 16383;
        int col = idx >> 7, i = idx & 127;
        int kv = fold & 1, lr = fold >> 1, l = lr / 3, r = lr % 3;
        int s = RSarr[r];
        const float* W = (kv ? Wv : Wk) + (size_t)(l * 2 + s) * 16384;
        const float* rel = (kv ? m_rel : a_rel) + (size_t)(l * 3 + r) * 2048;
        int hh = col >> 4, f = col & 15;
        float sacc = 0.f;
#pragma unroll
        for (int d = 0; d < 16; ++d)
            sacc += W[(size_t)i * 128 + hh * 16 + d] * rel[hh * 256 + d * 16 + f];
        wfT[gid] = f2bf(sacc);
        return;
    }
    int g = gid - NW;
    if (g >= L * 6 * 128) return;
    int fold = g >> 7, col = g & 127;
    int kv = fold & 1, lr = fold >> 1, l = lr / 3, r = lr % 3;
    int s = RSarr[r];
    const float* b = (kv ? bv : bk) + (size_t)(l * 2 + s) * 128;
    const float* rel = (kv ? m_rel : a_rel) + (size_t)(l * 3 + r) * 2048;
    int hh = col >> 4, f = col & 15;
    float sacc = 0.f;
#pragma unroll
    for (int d = 0; d < 16; ++d) sacc += b[hh * 16 + d] * rel[hh * 256 + d * 16 + f];
    bfold[fold * 128 + col] = sacc;
}

// ============ CSR build ============
__global__ void hist_kernel(const int* __restrict__ dst, int* __restrict__ cnt, int E) {
    int e = blockIdx.x * 256 + threadIdx.x;
    if (e < E) atomicAdd(&cnt[dst[e]], 1);
}

__global__ __launch_bounds__(1024) void scanA_kernel(const int* __restrict__ cnt,
                                                     int* __restrict__ texcl,
                                                     int* __restrict__ bsums, int n) {
    __shared__ int s[1024];
    int t = threadIdx.x;
    int gid = blockIdx.x * 1024 + t;
    int x = (gid < n) ? cnt[gid] : 0;
    s[t] = x;
    __syncthreads();
    for (int off = 1; off < 1024; off <<= 1) {
        int v = (t >= off) ? s[t - off] : 0;
        __syncthreads();
        s[t] += v;
        __syncthreads();
    }
    if (gid < n) texcl[gid] = s[t] - x;
    if (t == 1023) bsums[blockIdx.x] = s[1023];
}

__global__ void scanB_kernel(int* bsums, int nb) {
    if (threadIdx.x == 0 && blockIdx.x == 0) {
        int run = 0;
        for (int i = 0; i < nb; ++i) { int t = bsums[i]; bsums[i] = run; run += t; }
    }
}

__global__ __launch_bounds__(1024) void scanC_kernel(const int* __restrict__ texcl,
                                                     const int* __restrict__ bsums,
                                                     int* __restrict__ indptr,
                                                     int* __restrict__ cursor, int n, int E) {
    int gid = blockIdx.x * 1024 + threadIdx.x;
    if (gid < n) {
        int v = texcl[gid] + bsums[blockIdx.x];
        indptr[gid] = v;
        cursor[gid] = v;
    }
    if (gid == 0) indptr[n] = E;
}

__global__ void scatter_kernel(const int* __restrict__ src, const int* __restrict__ dst,
                               int* __restrict__ cursor, int* __restrict__ ssrc, int E) {
    int e = blockIdx.x * 256 + threadIdx.x;
    if (e < E) {
        int p = atomicAdd(&cursor[dst[e]], 1);
        ssrc[p] = src[e];
    }
}

// ============ fused attention: all 3 relations, one dispatch ============
// Waves [0,N0): dst type0, dual chain (rel0, rel1). Waves [N0,N0+N1): dst type1, chain rel2.
// No-max softmax: w = exp2(clamp(t*p*log2e, +-40)) -- logits are O(1) by construction.
__device__ __forceinline__ int nth_idx(const int* __restrict__ ss, int beg, int n, int j,
                                       int lane, int& bat) {
    int ph = j & 63;
    if (j != 0 && ph == 0) bat = (j + lane < n) ? ss[beg + j + lane] : 0;
    return __shfl(bat, ph);
}

__device__ __forceinline__ void edge_step(unsigned int cur, const float qf[4], float p2,
                                          bool isV, float& s, float4& a) {
    f32x2 lo = __builtin_amdgcn_cvt_pk_f32_fp8(cur, false);
    f32x2 hi = __builtin_amdgcn_cvt_pk_f32_fp8(cur, true);
    float t = qf[0] * lo[0] + qf[1] * lo[1] + qf[2] * hi[0] + qf[3] * hi[1];
    t += __shfl_xor(t, 1);
    t += __shfl_xor(t, 2);
    float tc = __shfl_xor(t, 32);
    if (isV) t = tc;
    float e = fminf(fmaxf(t * p2, -40.f), 40.f);
    float w = exp2f(e);
    s += w;
    a.x += w * lo[0]; a.y += w * lo[1]; a.z += w * hi[0]; a.w += w * hi[1];
}

__global__ __launch_bounds__(256) void attn_fused(
    const unsigned short* __restrict__ q0, const unsigned short* __restrict__ q1,
    const unsigned char* __restrict__ kvA, const unsigned char* __restrict__ kvB,
    const unsigned char* __restrict__ kvC,
    const int* __restrict__ ipA, const int* __restrict__ ssA,
    const int* __restrict__ ipB, const int* __restrict__ ssB,
    const int* __restrict__ ipC, const int* __restrict__ ssC,
    float* __restrict__ agg0, float* __restrict__ agg1,
    const float* __restrict__ prA, const float* __restrict__ prB,
    const float* __restrict__ prC, int N0, int N1) {
    int wave = (blockIdx.x * blockDim.x + threadIdx.x) >> 6;
    int lane = threadIdx.x & 63;
    if (wave >= N0 + N1) return;
    const int lq = lane & 31;
    const int head = lq >> 2;
    const bool isV = lane >= 32;
    const float LOG2E = 1.4426950408889634f;

    const unsigned short* qp;
    const unsigned char *kv1, *kv2;
    const int *ss1, *ss2;
    int b1, n1, b2, n2;
    float p1, p2;
    float* aggp;
    if (wave < N0) {
        qp = q0 + (size_t)wave * 128;
        kv1 = kvA; kv2 = kvB;
        b1 = ipA[wave]; n1 = ipA[wave + 1] - b1;
        b2 = ipB[wave]; n2 = ipB[wave + 1] - b2;
        ss1 = ssA; ss2 = ssB;
        p1 = prA[head] * 0.25f * LOG2E;
        p2 = prB[head] * 0.25f * LOG2E;
        aggp = agg0 + (size_t)wave * 128;
    } else {
        int d = wave - N0;
        qp = q1 + (size_t)d * 128;
        kv1 = kvC; kv2 = nullptr;
        b1 = ipC[d]; n1 = ipC[d + 1] - b1;
        b2 = 0; n2 = 0;
        ss1 = ssC; ss2 = nullptr;
        p1 = prC[head] * 0.25f * LOG2E;
        p2 = 0.f;
        aggp = agg1 + (size_t)d * 128;
    }

    float qf[4];
    {
        ushort4 qv = *reinterpret_cast<const ushort4*>(qp + lq * 4);
        qf[0] = bf2f(qv.x); qf[1] = bf2f(qv.y); qf[2] = bf2f(qv.z); qf[3] = bf2f(qv.w);
    }

    int bat1 = 0, bat2 = 0;
    unsigned int cur1 = 0, cur2 = 0;
    if (n1 > 0) {
        bat1 = (lane < n1) ? ss1[b1 + lane] : 0;
        int s0 = __shfl(bat1, 0);
        cur1 = *reinterpret_cast<const unsigned int*>(kv1 + (size_t)s0 * 256 + lane * 4);
    }
    if (n2 > 0) {
        bat2 = (lane < n2) ? ss2[b2 + lane] : 0;
        int s0 = __shfl(bat2, 0);
        cur2 = *reinterpret_cast<const unsigned int*>(kv2 + (size_t)s0 * 256 + lane * 4);
    }

    float s1a = 0.f, s2a = 0.f;
    float4 a1 = make_float4(0.f, 0.f, 0.f, 0.f);
    float4 a2 = make_float4(0.f, 0.f, 0.f, 0.f);
    int nmax = (n1 > n2) ? n1 : n2;
    for (int i = 0; i < nmax; ++i) {
        unsigned int nxt1 = 0, nxt2 = 0;
        if (i + 1 < n1) {
            int s = nth_idx(ss1, b1, n1, i + 1, lane, bat1);
            nxt1 = *reinterpret_cast<const unsigned int*>(kv1 + (size_t)s * 256 + lane * 4);
        }
        if (i + 1 < n2) {
            int s = nth_idx(ss2, b2, n2, i + 1, lane, bat2);
            nxt2 = *reinterpret_cast<const unsigned int*>(kv2 + (size_t)s * 256 + lane * 4);
        }
        if (i < n1) edge_step(cur1, qf, p1, isV, s1a, a1);
        if (i < n2) edge_step(cur2, qf, p2, isV, s2a, a2);
        cur1 = nxt1; cur2 = nxt2;
    }

    if (isV) {
        float i1 = 1.f / fmaxf(s1a, 1e-16f);
        float i2 = 1.f / fmaxf(s2a, 1e-16f);
        float4 r = make_float4(a1.x * i1 + a2.x * i2, a1.y * i1 + a2.y * i2,
                               a1.z * i1 + a2.z * i2, a1.w * i1 + a2.w * i2);
        *reinterpret_cast<float4*>(aggp + lq * 4) = r;
    }
}

// ============ readout ============
__global__ void colsum_kernel(const unsigned short* __restrict__ h, float* __restrict__ gsum,
                              int M) {
    int c = threadIdx.x;
    float s = 0.f;
    for (int r = blockIdx.x; r < M; r += gridDim.x) s += bf2f(h[(size_t)r * 128 + c]);
    atomicAdd(&gsum[c], s);
}

__global__ void final_kernel(const float* __restrict__ gsum, const float* __restrict__ Wc1,
                             const float* __restrict__ bc1, const float* __restrict__ Wc2,
                             const float* __restrict__ bc2, float* __restrict__ out,
                             float invM) {
    __shared__ float g[128];
    __shared__ float red[128];
    int t = threadIdx.x;
    g[t] = gsum[t] * invM;
    __syncthreads();
    float acc = bc1[t];
    for (int k = 0; k < 128; ++k) acc += g[k] * Wc1[k * 128 + t];
    float zv = fmaxf(acc, 0.f);
    red[t] = zv * Wc2[t];
    __syncthreads();
    for (int off = 64; off > 0; off >>= 1) {
        if (t < off) red[t] += red[t + off];
        __syncthreads();
    }
    if (t == 0) out[0] = 1.f / (1.f + expf(-(red[0] + bc2[0])));
}

extern "C" void kernel_launch(void* const* d_in, const int* in_sizes, int n_in,
                              void* d_out, int out_size, void* d_ws, size_t ws_size,
                              hipStream_t stream) {
    const float* x[2] = {(const float*)d_in[0], (const float*)d_in[1]};
    const int* edges[3] = {(const int*)d_in[2], (const int*)d_in[3], (const int*)d_in[4]};
    const float* Win[2] = {(const float*)d_in[5], (const float*)d_in[7]};
    const float* bin[2] = {(const float*)d_in[6], (const float*)d_in[8]};
    const float* Wk = (const float*)d_in[9];
    const float* bk = (const float*)d_in[10];
    const float* Wq = (const float*)d_in[11];
    const float* bq = (const float*)d_in[12];
    const float* Wv = (const float*)d_in[13];
    const float* bv = (const float*)d_in[14];
    const float* a_rel = (const float*)d_in[15];
    const float* m_rel = (const float*)d_in[16];
    const float* p_rel = (const float*)d_in[17];
    const float* Wa = (const float*)d_in[18];
    const float* ba = (const float*)d_in[19];
    const float* skip = (const float*)d_in[20];
    const float* Wc1 = (const float*)d_in[21];
    const float* bc1 = (const float*)d_in[22];
    const float* Wc2 = (const float*)d_in[23];
    const float* bc2 = (const float*)d_in[24];

    const int N0 = in_sizes[0] / 64;
    const int N1 = in_sizes[1] / 64;
    const int L = in_sizes[9] / (2 * 128 * 128);
    const int Ns[2] = {N0, N1};
    const int RD[3] = {0, 0, 1};
    const int Nmax = (N0 > N1) ? N0 : N1;

    char* p = (char*)d_ws;
    auto alloc = [&](size_t bytes) -> void* {
        void* r = (void*)p;
        p += (bytes + 255) & ~(size_t)255;
        return r;
    };
    unsigned short* h[2];
    unsigned short* q[2];
    float* agg[2];
    h[0] = (unsigned short*)alloc((size_t)N0 * 128 * 2);
    h[1] = (unsigned short*)alloc((size_t)N1 * 128 * 2);
    q[0] = (unsigned short*)alloc((size_t)N0 * 128 * 2);
    q[1] = (unsigned short*)alloc((size_t)N1 * 128 * 2);
    agg[0] = (float*)alloc((size_t)N0 * 128 * 4);
    agg[1] = (float*)alloc((size_t)N1 * 128 * 4);
    unsigned char* kv8[3];
    for (int r = 0; r < 3; ++r) kv8[r] = (unsigned char*)alloc((size_t)Nmax * 256);
    int* indptr[3];
    int* ssrc[3];
    int Er[3];
    for (int r = 0; r < 3; ++r) {
        Er[r] = in_sizes[2 + r] / 2;
        indptr[r] = (int*)alloc((size_t)(Ns[RD[r]] + 1) * 4);
        ssrc[r] = (int*)alloc((size_t)Er[r] * 4);
    }
    int* cnt = (int*)alloc((size_t)Nmax * 4);
    int* texcl = (int*)alloc((size_t)Nmax * 4);
    int* bsums = (int*)alloc(256 * 4);
    unsigned short* winT = (unsigned short*)alloc(2 * 8192 * 2);
    unsigned short* wqT = (unsigned short*)alloc((size_t)L * 2 * 16384 * 2);
    unsigned short* waT = (unsigned short*)alloc((size_t)L * 2 * 16384 * 2);
    unsigned short* wfT = (unsigned short*)alloc((size_t)L * 6 * 16384 * 2);
    float* bfold = (float*)alloc((size_t)L * 6 * 128 * 4);
    float* gsum = (float*)alloc(128 * 4);

    // ---- weight prep ----
    {
        int nmat = L * 2;
        int convN = 2 * 8192 + 2 * nmat * 16384;
        convT_kernel<<<(convN + 255) / 256, 256, 0, stream>>>(Win[0], Win[1], Wq, Wa, winT, wqT,
                                                              waT, nmat);
        int foldN = L * 6 * 16384 + L * 6 * 128;
        fold_kernel<<<(foldN + 255) / 256, 256, 0, stream>>>(Wk, bk, Wv, bv, a_rel, m_rel, wfT,
                                                             bfold, L);
    }

    // ---- CSR build ----
    for (int r = 0; r < 3; ++r) {
        int Nd = Ns[RD[r]];
        int E = Er[r];
        int nb = (Nd + 1023) / 1024;
        hipMemsetAsync(cnt, 0, (size_t)Nd * 4, stream);
        hist_kernel<<<(E + 255) / 256, 256, 0, stream>>>(edges[r] + E, cnt, E);
        scanA_kernel<<<nb, 1024, 0, stream>>>(cnt, texcl, bsums, Nd);
        scanB_kernel<<<1, 64, 0, stream>>>(bsums, nb);
        scanC_kernel<<<nb, 1024, 0, stream>>>(texcl, bsums, indptr[r], cnt, Nd, E);
        scatter_kernel<<<(E + 255) / 256, 256, 0, stream>>>(edges[r], edges[r] + E, cnt, ssrc[r],
                                                            E);
    }

    // ---- input projection ----
    for (int t = 0; t < 2; ++t) {
        gemm_mfma<64, 1, 1><<<(Ns[t] + 127) / 128, 256, 0, stream>>>(
            x[t], winT + t * 8192, bin[t], h[t], Ns[t], nullptr, nullptr);
    }

    // ---- layers ----
    for (int l = 0; l < L; ++l) {
        {
            QKVJobs J{};
            J.BT[0] = wqT + (size_t)(l * 2 + 0) * 16384;
            J.bias[0] = bq + (size_t)(l * 2 + 0) * 128;
            J.outBf[0] = q[0]; J.outF8[0] = nullptr; J.f8off[0] = 0;
            int fk0 = (l * 3 + 0) * 2, fk2 = (l * 3 + 2) * 2;
            J.BT[1] = wfT + (size_t)fk0 * 16384;       J.bias[1] = bfold + (size_t)fk0 * 128;
            J.outBf[1] = nullptr; J.outF8[1] = kv8[0]; J.f8off[1] = 0;
            J.BT[2] = wfT + (size_t)(fk0 + 1) * 16384; J.bias[2] = bfold + (size_t)(fk0 + 1) * 128;
            J.outBf[2] = nullptr; J.outF8[2] = kv8[0]; J.f8off[2] = 128;
            J.BT[3] = wfT + (size_t)fk2 * 16384;       J.bias[3] = bfold + (size_t)fk2 * 128;
            J.outBf[3] = nullptr; J.outF8[3] = kv8[2]; J.f8off[3] = 0;
            J.BT[4] = wfT + (size_t)(fk2 + 1) * 16384; J.bias[4] = bfold + (size_t)(fk2 + 1) * 128;
            J.outBf[4] = nullptr; J.outF8[4] = kv8[2]; J.f8off[4] = 128;
            gemm_qkv<5><<<(N0 + 127) / 128, 256, 0, stream>>>(h[0], J, N0);
        }
        {
            QKVJobs J{};
            J.BT[0] = wqT + (size_t)(l * 2 + 1) * 16384;
            J.bias[0] = bq + (size_t)(l * 2 + 1) * 128;
            J.outBf[0] = q[1]; J.outF8[0] = nullptr; J.f8off[0] = 0;
            int fk1 = (l * 3 + 1) * 2;
            J.BT[1] = wfT + (size_t)fk1 * 16384;       J.bias[1] = bfold + (size_t)fk1 * 128;
            J.outBf[1] = nullptr; J.outF8[1] = kv8[1]; J.f8off[1] = 0;
            J.BT[2] = wfT + (size_t)(fk1 + 1) * 16384; J.bias[2] = bfold + (size_t)(fk1 + 1) * 128;
            J.outBf[2] = nullptr; J.outF8[2] = kv8[1]; J.f8off[2] = 128;
            gemm_qkv<3><<<(N1 + 127) / 128, 256, 0, stream>>>(h[1], J, N1);
        }
        // fused attention (all relations, both dst types, one dispatch)
        {
            int W = N0 + N1;
            attn_fused<<<(W + 3) / 4, 256, 0, stream>>>(
                q[0], q[1], kv8[0], kv8[1], kv8[2], indptr[0], ssrc[0], indptr[1], ssrc[1],
                indptr[2], ssrc[2], agg[0], agg[1], p_rel + (size_t)(l * 3 + 0) * 8,
                p_rel + (size_t)(l * 3 + 1) * 8, p_rel + (size_t)(l * 3 + 2) * 8, N0, N1);
        }
        // output projection + skip
        for (int t = 0; t < 2; ++t) {
            gemm_mfma<128, 2, 1><<<(Ns[t] + 127) / 128, 256, 0, stream>>>(
                agg[t], waT + (size_t)(l * 2 + t) * 16384, ba + (size_t)(l * 2 + t) * 128, h[t],
                Ns[t], h[t], skip + (size_t)(l * 2 + t));
        }
    }

    // ---- readout ----
    hipMemsetAsync(gsum, 0, 128 * 4, stream);
    colsum_kernel<<<512, 128, 0, stream>>>(h[0], gsum, N0);
    final_kernel<<<1, 128, 0, stream>>>(gsum, Wc1, bc1, Wc2, bc2, (float*)d_out,
                                        1.0f / (float)N0);
}

// Round 5
// 708.291 us; speedup vs baseline: 2.4145x; 1.1707x over previous
//
#include <hip/hip_runtime.h>
#include <hip/hip_fp8.h>
#include <math.h>

typedef __attribute__((ext_vector_type(8))) short short8v;   // 8 x bf16 (4 VGPRs)
typedef __attribute__((ext_vector_type(4))) float f32x4;
typedef __attribute__((ext_vector_type(2))) float f32x2;

__device__ __forceinline__ float bf2f(unsigned short u) {
    union { unsigned int i; float f; } x; x.i = ((unsigned int)u) << 16; return x.f;
}
__device__ __forceinline__ unsigned short f2bf(float f) {
    union { float f; unsigned int i; } x; x.f = f;
    unsigned int r = x.i + 0x7fffu + ((x.i >> 16) & 1u);
    return (unsigned short)(r >> 16);
}
__device__ __forceinline__ unsigned char f2fp8(float f) {
    __hip_fp8_e4m3 t(f);
    return (unsigned char)t.__x;
}
__device__ __forceinline__ float gelu_exact(float x) {
    return 0.5f * x * (1.0f + erff(x * 0.70710678118654752f));
}

// ============ bf16 MFMA GEMM body (input/output projections) ============
template <int K, int MODE, int ASRC>
__device__ __forceinline__ void gemm_body(
    const void* __restrict__ Aptr, const unsigned short* __restrict__ BT,
    const float* __restrict__ bias, unsigned short* __restrict__ Cout, int M,
    const unsigned short* __restrict__ hprev, const float* __restrict__ skipp, int blk) {
    __shared__ short As[128 * K];
    __shared__ short Bs[128 * K];
    const int tid = threadIdx.x;
    const int row0 = blk * 128;
    const int CH = K / 8;

#pragma unroll
    for (int i = 0; i < (128 * CH) / 256; ++i) {
        int idx = tid + i * 256;
        int r = idx / CH, c = idx % CH;
        int gr = row0 + r;
        short8v val = {0, 0, 0, 0, 0, 0, 0, 0};
        if (gr < M) {
            if (ASRC == 0) {
                val = *reinterpret_cast<const short8v*>(
                    (const unsigned short*)Aptr + (size_t)gr * K + c * 8);
            } else {
                const float* Af = (const float*)Aptr;
                float4 f0 = *reinterpret_cast<const float4*>(Af + (size_t)gr * K + c * 8);
                float4 f1 = *reinterpret_cast<const float4*>(Af + (size_t)gr * K + c * 8 + 4);
                float fa[8] = {f0.x, f0.y, f0.z, f0.w, f1.x, f1.y, f1.z, f1.w};
#pragma unroll
                for (int u = 0; u < 8; ++u) {
                    float fv = fa[u];
                    if (MODE == 2) fv = gelu_exact(fv);
                    val[u] = (short)f2bf(fv);
                }
            }
        }
        *reinterpret_cast<short8v*>((char*)As + r * (2 * K) + ((c * 16) ^ ((r & 7) << 4))) = val;
    }
#pragma unroll
    for (int i = 0; i < (128 * CH) / 256; ++i) {
        int idx = tid + i * 256;
        int r = idx / CH, c = idx % CH;
        short8v val = *reinterpret_cast<const short8v*>(BT + (size_t)r * K + c * 8);
        *reinterpret_cast<short8v*>((char*)Bs + r * (2 * K) + ((c * 16) ^ ((r & 7) << 4))) = val;
    }
    __syncthreads();

    const int lane = tid & 63, wid = tid >> 6;
    const int wr = wid >> 1, wc = wid & 1;
    const int lr = lane & 15, lg = lane >> 4;
    const int swz = (lr & 7) << 4;
    f32x4 acc[4][4];
    f32x4 z4 = {0.f, 0.f, 0.f, 0.f};
#pragma unroll
    for (int mi = 0; mi < 4; ++mi)
#pragma unroll
        for (int ni = 0; ni < 4; ++ni) acc[mi][ni] = z4;

#pragma unroll
    for (int ks = 0; ks < K / 32; ++ks) {
        int kc = ks * 64 + lg * 16;
        short8v a[4], b[4];
#pragma unroll
        for (int mi = 0; mi < 4; ++mi) {
            int r = wr * 64 + mi * 16 + lr;
            a[mi] = *reinterpret_cast<const short8v*>((char*)As + r * (2 * K) + (kc ^ swz));
        }
#pragma unroll
        for (int ni = 0; ni < 4; ++ni) {
            int r = wc * 64 + ni * 16 + lr;
            b[ni] = *reinterpret_cast<const short8v*>((char*)Bs + r * (2 * K) + (kc ^ swz));
        }
#pragma unroll
        for (int mi = 0; mi < 4; ++mi)
#pragma unroll
            for (int ni = 0; ni < 4; ++ni)
                acc[mi][ni] =
                    __builtin_amdgcn_mfma_f32_16x16x32_bf16(a[mi], b[ni], acc[mi][ni], 0, 0, 0);
    }

    float beta = 0.f;
    if (MODE == 2) beta = 1.f / (1.f + expf(-skipp[0]));
#pragma unroll
    for (int mi = 0; mi < 4; ++mi) {
#pragma unroll
        for (int ni = 0; ni < 4; ++ni) {
            int col = wc * 64 + ni * 16 + lr;
            float bv = bias[col];
#pragma unroll
            for (int j = 0; j < 4; ++j) {
                int gr = row0 + wr * 64 + mi * 16 + lg * 4 + j;
                if (gr < M) {
                    float v = acc[mi][ni][j] + bv;
                    if (MODE == 1) v = fmaxf(v, 0.f);
                    if (MODE == 2) v = beta * v + (1.f - beta) * bf2f(hprev[(size_t)gr * 128 + col]);
                    Cout[(size_t)gr * 128 + col] = f2bf(v);
                }
            }
        }
    }
}

template <int K, int MODE, int ASRC>
__global__ __launch_bounds__(256) void gemm_dual(
    const void* A0, const unsigned short* BT0, const float* b0, unsigned short* C0, int M0,
    const unsigned short* hp0, const float* sk0,
    const void* A1, const unsigned short* BT1, const float* b1, unsigned short* C1, int M1,
    const unsigned short* hp1, const float* sk1, int nb0) {
    if ((int)blockIdx.x < nb0)
        gemm_body<K, MODE, ASRC>(A0, BT0, b0, C0, M0, hp0, sk0, blockIdx.x);
    else
        gemm_body<K, MODE, ASRC>(A1, BT1, b1, C1, M1, hp1, sk1, blockIdx.x - nb0);
}

// ============ fused QKV GEMM: one A-tile, up to 5 B-matrices ============
// fp8 out layout: row = 32 chunks x 8B; chunk c bytes [8c..8c+3] = K cols 4c..4c+3,
// bytes [8c+4..8c+7] = V cols 4c..4c+3.  f8off: 0 for K, 4 for V.
struct QKVJobs {
    const unsigned short* BT[5];
    const float* bias[5];
    unsigned short* outBf[5];
    unsigned char* outF8[5];
    int f8off[5];
};

__device__ __forceinline__ void qkv_body(const unsigned short* __restrict__ A,
                                         const QKVJobs& J, int M, int nj, int blk) {
    __shared__ short As[128 * 128];
    __shared__ short Bs[128 * 128];
    const int tid = threadIdx.x;
    const int row0 = blk * 128;

    short8v breg[8];
#pragma unroll
    for (int i = 0; i < 8; ++i) {
        int idx = tid + i * 256;
        int r = idx >> 4, c = idx & 15;
        breg[i] = *reinterpret_cast<const short8v*>(J.BT[0] + (size_t)r * 128 + c * 8);
    }
#pragma unroll
    for (int i = 0; i < 8; ++i) {
        int idx = tid + i * 256;
        int r = idx >> 4, c = idx & 15;
        int gr = row0 + r;
        short8v val = {0, 0, 0, 0, 0, 0, 0, 0};
        if (gr < M) val = *reinterpret_cast<const short8v*>(A + (size_t)gr * 128 + c * 8);
        *reinterpret_cast<short8v*>((char*)As + r * 256 + ((c * 16) ^ ((r & 7) << 4))) = val;
    }
#pragma unroll
    for (int i = 0; i < 8; ++i) {
        int idx = tid + i * 256;
        int r = idx >> 4, c = idx & 15;
        *reinterpret_cast<short8v*>((char*)Bs + r * 256 + ((c * 16) ^ ((r & 7) << 4))) = breg[i];
    }

    const int lane = tid & 63, wid = tid >> 6;
    const int wr = wid >> 1, wc = wid & 1;
    const int lr = lane & 15, lg = lane >> 4;
    const int swz = (lr & 7) << 4;

    for (int m = 0; m < nj; ++m) {
        if (m + 1 < nj) {
#pragma unroll
            for (int i = 0; i < 8; ++i) {
                int idx = tid + i * 256;
                int r = idx >> 4, c = idx & 15;
                breg[i] = *reinterpret_cast<const short8v*>(J.BT[m + 1] + (size_t)r * 128 + c * 8);
            }
        }
        __syncthreads();

        f32x4 acc[4][4];
        f32x4 z4 = {0.f, 0.f, 0.f, 0.f};
#pragma unroll
        for (int mi = 0; mi < 4; ++mi)
#pragma unroll
            for (int ni = 0; ni < 4; ++ni) acc[mi][ni] = z4;

#pragma unroll
        for (int ks = 0; ks < 4; ++ks) {
            int kc = ks * 64 + lg * 16;
            short8v a[4], b[4];
#pragma unroll
            for (int mi = 0; mi < 4; ++mi) {
                int r = wr * 64 + mi * 16 + lr;
                a[mi] = *reinterpret_cast<const short8v*>((char*)As + r * 256 + (kc ^ swz));
            }
#pragma unroll
            for (int ni = 0; ni < 4; ++ni) {
                int r = wc * 64 + ni * 16 + lr;
                b[ni] = *reinterpret_cast<const short8v*>((char*)Bs + r * 256 + (kc ^ swz));
            }
#pragma unroll
            for (int mi = 0; mi < 4; ++mi)
#pragma unroll
                for (int ni = 0; ni < 4; ++ni)
                    acc[mi][ni] = __builtin_amdgcn_mfma_f32_16x16x32_bf16(a[mi], b[ni],
                                                                          acc[mi][ni], 0, 0, 0);
        }
        __syncthreads();
        if (m + 1 < nj) {
#pragma unroll
            for (int i = 0; i < 8; ++i) {
                int idx = tid + i * 256;
                int r = idx >> 4, c = idx & 15;
                *reinterpret_cast<short8v*>((char*)Bs + r * 256 + ((c * 16) ^ ((r & 7) << 4))) =
                    breg[i];
            }
        }

        unsigned short* outBf = J.outBf[m];
        unsigned char* outF8 = J.outF8[m];
        int off = J.f8off[m];
        const float* bias = J.bias[m];
#pragma unroll
        for (int mi = 0; mi < 4; ++mi) {
#pragma unroll
            for (int ni = 0; ni < 4; ++ni) {
                int col = wc * 64 + ni * 16 + lr;
                float bv = bias[col];
                int bpos = ((col & 124) << 1) + off + (col & 3);
#pragma unroll
                for (int j = 0; j < 4; ++j) {
                    int gr = row0 + wr * 64 + mi * 16 + lg * 4 + j;
                    if (gr < M) {
                        float v = acc[mi][ni][j] + bv;
                        if (outBf) outBf[(size_t)gr * 128 + col] = f2bf(v);
                        else outF8[(size_t)gr * 256 + bpos] = f2fp8(v);
                    }
                }
            }
        }
    }
}

__global__ __launch_bounds__(256) void gemm_qkv2(const unsigned short* A0, QKVJobs J0, int M0,
                                                 int nj0, int nb0, const unsigned short* A1,
                                                 QKVJobs J1, int M1, int nj1) {
    if ((int)blockIdx.x < nb0) qkv_body(A0, J0, M0, nj0, blockIdx.x);
    else qkv_body(A1, J1, M1, nj1, blockIdx.x - nb0);
}

// ============ weight prep ============
__global__ void convT_kernel(const float* __restrict__ Win0, const float* __restrict__ Win1,
                             const float* __restrict__ Wq, const float* __restrict__ Wa,
                             unsigned short* __restrict__ winT, unsigned short* __restrict__ wqT,
                             unsigned short* __restrict__ waT, int nmat) {
    int gid = blockIdx.x * 256 + threadIdx.x;
    if (gid < 2 * 8192) {
        int m = gid >> 13, idx = gid & 8191;
        int n = idx >> 6, k = idx & 63;
        const float* W = m ? Win1 : Win0;
        winT[gid] = f2bf(W[(size_t)k * 128 + n]);
        return;
    }
    int g = gid - 2 * 8192;
    if (g < nmat * 16384) {
        int mat = g >> 14, idx = g & 16383;
        int n = idx >> 7, k = idx & 127;
        wqT[g] = f2bf(Wq[(size_t)mat * 16384 + (size_t)k * 128 + n]);
        return;
    }
    g -= nmat * 16384;
    if (g < nmat * 16384) {
        int mat = g >> 14, idx = g & 16383;
        int n = idx >> 7, k = idx & 127;
        waT[g] = f2bf(Wa[(size_t)mat * 16384 + (size_t)k * 128 + n]);
    }
}

// ============ relation fold ============
__global__ void fold_kernel(const float* __restrict__ Wk, const float* __restrict__ bk,
                            const float* __restrict__ Wv, const float* __restrict__ bv,
                            const float* __restrict__ a_rel, const float* __restrict__ m_rel,
                            unsigned short* __restrict__ wfT, float* __restrict__ bfold, int L) {
    const int RSarr[3] = {0, 1, 0};
    int gid = blockIdx.x * 256 + threadIdx.x;
    int NW = L * 6 * 16384;
    if (gid < NW) {
        int fold = gid >> 14, idx = gid & 16383;
        int col = idx >> 7, i = idx & 127;
        int kv = fold & 1, lr = fold >> 1, l = lr / 3, r = lr % 3;
        int s = RSarr[r];
        const float* W = (kv ? Wv : Wk) + (size_t)(l * 2 + s) * 16384;
        const float* rel = (kv ? m_rel : a_rel) + (size_t)(l * 3 + r) * 2048;
        int hh = col >> 4, f = col & 15;
        float sacc = 0.f;
#pragma unroll
        for (int d = 0; d < 16; ++d)
            sacc += W[(size_t)i * 128 + hh * 16 + d] * rel[hh * 256 + d * 16 + f];
        wfT[gid] = f2bf(sacc);
        return;
    }
    int g = gid - NW;
    if (g >= L * 6 * 128) return;
    int fold = g >> 7, col = g & 127;
    int kv = fold & 1, lr = fold >> 1, l = lr / 3, r = lr % 3;
    int s = RSarr[r];
    const float* b = (kv ? bv : bk) + (size_t)(l * 2 + s) * 128;
    const float* rel = (kv ? m_rel : a_rel) + (size_t)(l * 3 + r) * 2048;
    int hh = col >> 4, f = col & 15;
    float sacc = 0.f;
#pragma unroll
    for (int d = 0; d < 16; ++d) sacc += b[hh * 16 + d] * rel[hh * 256 + d * 16 + f];
    bfold[fold * 128 + col] = sacc;
}

// ============ merged CSR build (all 3 relations) ============
struct Csr3 {
    const int* src[3];
    const int* dst[3];
    int E[3];
    int* cnt;      // 3*stride ints (later reused as cursor)
    int* texcl;    // 3*stride
    int* bsums;    // 3*64
    int* indptr[3];
    int* ssrc[3];
    int Nd[3];
    int nb[3];
    int stride;
};

__global__ void hist3_kernel(Csr3 P, int Etot) {
    int gid = blockIdx.x * 256 + threadIdx.x;
    if (gid >= Etot) return;
    int r = 0, off = gid;
    if (off >= P.E[0]) { off -= P.E[0]; r = 1; if (off >= P.E[1]) { off -= P.E[1]; r = 2; } }
    atomicAdd(&P.cnt[r * P.stride + P.dst[r][off]], 1);
}

__global__ __launch_bounds__(1024) void scanA3_kernel(Csr3 P) {
    __shared__ int s[1024];
    int b = blockIdx.x, r = 0;
    while (b >= P.nb[r]) { b -= P.nb[r]; ++r; }
    const int* cnt = P.cnt + r * P.stride;
    int* texcl = P.texcl + r * P.stride;
    int n = P.Nd[r];
    int t = threadIdx.x;
    int gid = b * 1024 + t;
    int x = (gid < n) ? cnt[gid] : 0;
    s[t] = x;
    __syncthreads();
    for (int off = 1; off < 1024; off <<= 1) {
        int v = (t >= off) ? s[t - off] : 0;
        __syncthreads();
        s[t] += v;
        __syncthreads();
    }
    if (gid < n) texcl[gid] = s[t] - x;
    if (t == 1023) P.bsums[r * 64 + b] = s[1023];
}

__global__ void scanB3_kernel(Csr3 P) {
    int r = blockIdx.x;
    if (threadIdx.x == 0) {
        int run = 0;
        for (int i = 0; i < P.nb[r]; ++i) {
            int t = P.bsums[r * 64 + i];
            P.bsums[r * 64 + i] = run;
            run += t;
        }
    }
}

__global__ __launch_bounds__(1024) void scanC3_kernel(Csr3 P) {
    int b = blockIdx.x, r = 0;
    while (b >= P.nb[r]) { b -= P.nb[r]; ++r; }
    int n = P.Nd[r];
    int gid = b * 1024 + threadIdx.x;
    if (gid < n) {
        int v = P.texcl[r * P.stride + gid] + P.bsums[r * 64 + b];
        P.indptr[r][gid] = v;
        P.cnt[r * P.stride + gid] = v;  // cursor
    }
    if (gid == 0) P.indptr[r][n] = P.E[r];
}

__global__ void scatter3_kernel(Csr3 P, int Etot) {
    int gid = blockIdx.x * 256 + threadIdx.x;
    if (gid >= Etot) return;
    int r = 0, off = gid;
    if (off >= P.E[0]) { off -= P.E[0]; r = 1; if (off >= P.E[1]) { off -= P.E[1]; r = 2; } }
    int d = P.dst[r][off];
    int p = atomicAdd(&P.cnt[r * P.stride + d], 1);
    P.ssrc[r][p] = P.src[r][off];
}

// ============ attention: 2 dsts per wave (32 lanes each), fp8 interleaved kv ============
// kv row: 32 chunks x 8B; lane lq handles cols 4lq..4lq+3 of K (bytes .x) and V (bytes .y).
// head = lq>>2; dot-reduce via shfl_xor 1,2 within the 4-lane head group.
__device__ __forceinline__ void run_chain(const unsigned char* __restrict__ kv,
                                          const int* __restrict__ ss, int beg, int n,
                                          const float qf[4], float psc, int lq, int lhb,
                                          float& ssum, float4& acc) {
    if (n <= 0) return;
    int bat = (lq < n) ? ss[beg + lq] : 0;
    int s0 = __shfl(bat, lhb);
    uint2 cur = *reinterpret_cast<const uint2*>(kv + (size_t)s0 * 256 + lq * 8);
    for (int i = 0; i < n; ++i) {
        uint2 nxt = make_uint2(0u, 0u);
        int j = i + 1;
        if (j < n) {
            int ph = j & 31;
            if (ph == 0) bat = (j + lq < n) ? ss[beg + j + lq] : 0;
            int s = __shfl(bat, lhb + ph);
            nxt = *reinterpret_cast<const uint2*>(kv + (size_t)s * 256 + lq * 8);
        }
        f32x2 klo = __builtin_amdgcn_cvt_pk_f32_fp8(cur.x, false);
        f32x2 khi = __builtin_amdgcn_cvt_pk_f32_fp8(cur.x, true);
        float t = qf[0] * klo[0] + qf[1] * klo[1] + qf[2] * khi[0] + qf[3] * khi[1];
        t += __shfl_xor(t, 1);
        t += __shfl_xor(t, 2);
        float e = fminf(fmaxf(t * psc, -40.f), 40.f);
        float w = exp2f(e);
        f32x2 vlo = __builtin_amdgcn_cvt_pk_f32_fp8(cur.y, false);
        f32x2 vhi = __builtin_amdgcn_cvt_pk_f32_fp8(cur.y, true);
        ssum += w;
        acc.x += w * vlo[0];
        acc.y += w * vlo[1];
        acc.z += w * vhi[0];
        acc.w += w * vhi[1];
        cur = nxt;
    }
}

__global__ __launch_bounds__(256) void attn_fused(
    const unsigned short* __restrict__ q0, const unsigned short* __restrict__ q1,
    const unsigned char* __restrict__ kvA, const unsigned char* __restrict__ kvB,
    const unsigned char* __restrict__ kvC,
    const int* __restrict__ ipA, const int* __restrict__ ssA,
    const int* __restrict__ ipB, const int* __restrict__ ssB,
    const int* __restrict__ ipC, const int* __restrict__ ssC,
    float* __restrict__ agg0, float* __restrict__ agg1,
    const float* __restrict__ prA, const float* __restrict__ prB,
    const float* __restrict__ prC, int N0, int N1) {
    const int wave = (blockIdx.x * blockDim.x + threadIdx.x) >> 6;
    const int lane = threadIdx.x & 63;
    const int lq = lane & 31;
    const int lhb = lane & 32;        // half base for shfl
    const int head = lq >> 2;
    const float LOG2E = 1.4426950408889634f;
    const int P0 = (N0 + 1) >> 1;
    const int P1 = (N1 + 1) >> 1;
    if (wave >= P0 + P1) return;

    if (wave < P0) {
        int dst = wave * 2 + (lhb >> 5);
        bool act = dst < N0;
        float qf[4] = {0.f, 0.f, 0.f, 0.f};
        int b1 = 0, n1 = 0, b2 = 0, n2 = 0;
        if (act) {
            ushort4 qv = *reinterpret_cast<const ushort4*>(q0 + (size_t)dst * 128 + lq * 4);
            qf[0] = bf2f(qv.x); qf[1] = bf2f(qv.y); qf[2] = bf2f(qv.z); qf[3] = bf2f(qv.w);
            b1 = ipA[dst]; n1 = ipA[dst + 1] - b1;
            b2 = ipB[dst]; n2 = ipB[dst + 1] - b2;
        }
        float pA = prA[head] * 0.25f * LOG2E;
        float pB = prB[head] * 0.25f * LOG2E;
        float s1 = 0.f, s2 = 0.f;
        float4 a1 = make_float4(0.f, 0.f, 0.f, 0.f);
        float4 a2 = make_float4(0.f, 0.f, 0.f, 0.f);
        run_chain(kvA, ssA, b1, n1, qf, pA, lq, lhb, s1, a1);
        run_chain(kvB, ssB, b2, n2, qf, pB, lq, lhb, s2, a2);
        if (act) {
            float i1 = 1.f / fmaxf(s1, 1e-16f);
            float i2 = 1.f / fmaxf(s2, 1e-16f);
            float4 r = make_float4(a1.x * i1 + a2.x * i2, a1.y * i1 + a2.y * i2,
                                   a1.z * i1 + a2.z * i2, a1.w * i1 + a2.w * i2);
            *reinterpret_cast<float4*>(agg0 + (size_t)dst * 128 + lq * 4) = r;
        }
    } else {
        int dst = (wave - P0) * 2 + (lhb >> 5);
        bool act = dst < N1;
        float qf[4] = {0.f, 0.f, 0.f, 0.f};
        int b1 = 0, n1 = 0;
        if (act) {
            ushort4 qv = *reinterpret_cast<const ushort4*>(q1 + (size_t)dst * 128 + lq * 4);
            qf[0] = bf2f(qv.x); qf[1] = bf2f(qv.y); qf[2] = bf2f(qv.z); qf[3] = bf2f(qv.w);
            b1 = ipC[dst]; n1 = ipC[dst + 1] - b1;
        }
        float pC = prC[head] * 0.25f * LOG2E;
        float s1 = 0.f;
        float4 a1 = make_float4(0.f, 0.f, 0.f, 0.f);
        run_chain(kvC, ssC, b1, n1, qf, pC, lq, lhb, s1, a1);
        if (act) {
            float i1 = 1.f / fmaxf(s1, 1e-16f);
            float4 r = make_float4(a1.x * i1, a1.y * i1, a1.z * i1, a1.w * i1);
            *reinterpret_cast<float4*>(agg1 + (size_t)dst * 128 + lq * 4) = r;
        }
    }
}

// ============ readout ============
__global__ void colsum_kernel(const unsigned short* __restrict__ h, float* __restrict__ gsum,
                              int M) {
    int c = threadIdx.x;
    float s = 0.f;
    for (int r = blockIdx.x; r < M; r += gridDim.x) s += bf2f(h[(size_t)r * 128 + c]);
    atomicAdd(&gsum[c], s);
}

__global__ void final_kernel(const float* __restrict__ gsum, const float* __restrict__ Wc1,
                             const float* __restrict__ bc1, const float* __restrict__ Wc2,
                             const float* __restrict__ bc2, float* __restrict__ out,
                             float invM) {
    __shared__ float g[128];
    __shared__ float red[128];
    int t = threadIdx.x;
    g[t] = gsum[t] * invM;
    __syncthreads();
    float acc = bc1[t];
    for (int k = 0; k < 128; ++k) acc += g[k] * Wc1[k * 128 + t];
    float zv = fmaxf(acc, 0.f);
    red[t] = zv * Wc2[t];
    __syncthreads();
    for (int off = 64; off > 0; off >>= 1) {
        if (t < off) red[t] += red[t + off];
        __syncthreads();
    }
    if (t == 0) out[0] = 1.f / (1.f + expf(-(red[0] + bc2[0])));
}

extern "C" void kernel_launch(void* const* d_in, const int* in_sizes, int n_in,
                              void* d_out, int out_size, void* d_ws, size_t ws_size,
                              hipStream_t stream) {
    const float* x[2] = {(const float*)d_in[0], (const float*)d_in[1]};
    const int* edges[3] = {(const int*)d_in[2], (const int*)d_in[3], (const int*)d_in[4]};
    const float* Win[2] = {(const float*)d_in[5], (const float*)d_in[7]};
    const float* bin[2] = {(const float*)d_in[6], (const float*)d_in[8]};
    const float* Wk = (const float*)d_in[9];
    const float* bk = (const float*)d_in[10];
    const float* Wq = (const float*)d_in[11];
    const float* bq = (const float*)d_in[12];
    const float* Wv = (const float*)d_in[13];
    const float* bv = (const float*)d_in[14];
    const float* a_rel = (const float*)d_in[15];
    const float* m_rel = (const float*)d_in[16];
    const float* p_rel = (const float*)d_in[17];
    const float* Wa = (const float*)d_in[18];
    const float* ba = (const float*)d_in[19];
    const float* skip = (const float*)d_in[20];
    const float* Wc1 = (const float*)d_in[21];
    const float* bc1 = (const float*)d_in[22];
    const float* Wc2 = (const float*)d_in[23];
    const float* bc2 = (const float*)d_in[24];

    const int N0 = in_sizes[0] / 64;
    const int N1 = in_sizes[1] / 64;
    const int L = in_sizes[9] / (2 * 128 * 128);
    const int Ns[2] = {N0, N1};
    const int RD[3] = {0, 0, 1};
    const int Nmax = (N0 > N1) ? N0 : N1;

    char* p = (char*)d_ws;
    auto alloc = [&](size_t bytes) -> void* {
        void* r = (void*)p;
        p += (bytes + 255) & ~(size_t)255;
        return r;
    };
    unsigned short* h[2];
    unsigned short* q[2];
    float* agg[2];
    h[0] = (unsigned short*)alloc((size_t)N0 * 128 * 2);
    h[1] = (unsigned short*)alloc((size_t)N1 * 128 * 2);
    q[0] = (unsigned short*)alloc((size_t)N0 * 128 * 2);
    q[1] = (unsigned short*)alloc((size_t)N1 * 128 * 2);
    agg[0] = (float*)alloc((size_t)N0 * 128 * 4);
    agg[1] = (float*)alloc((size_t)N1 * 128 * 4);
    unsigned char* kv8[3];
    for (int r = 0; r < 3; ++r) kv8[r] = (unsigned char*)alloc((size_t)Nmax * 256);
    int* indptr[3];
    int* ssrc[3];
    int Er[3];
    for (int r = 0; r < 3; ++r) {
        Er[r] = in_sizes[2 + r] / 2;
        indptr[r] = (int*)alloc((size_t)(Ns[RD[r]] + 1) * 4);
        ssrc[r] = (int*)alloc((size_t)Er[r] * 4);
    }
    int* cnt3 = (int*)alloc((size_t)3 * Nmax * 4);
    int* texcl3 = (int*)alloc((size_t)3 * Nmax * 4);
    int* bsums3 = (int*)alloc(3 * 64 * 4);
    unsigned short* winT = (unsigned short*)alloc(2 * 8192 * 2);
    unsigned short* wqT = (unsigned short*)alloc((size_t)L * 2 * 16384 * 2);
    unsigned short* waT = (unsigned short*)alloc((size_t)L * 2 * 16384 * 2);
    unsigned short* wfT = (unsigned short*)alloc((size_t)L * 6 * 16384 * 2);
    float* bfold = (float*)alloc((size_t)L * 6 * 128 * 4);
    float* gsum = (float*)alloc(128 * 4);

    // ---- weight prep ----
    {
        int nmat = L * 2;
        int convN = 2 * 8192 + 2 * nmat * 16384;
        convT_kernel<<<(convN + 255) / 256, 256, 0, stream>>>(Win[0], Win[1], Wq, Wa, winT, wqT,
                                                              waT, nmat);
        int foldN = L * 6 * 16384 + L * 6 * 128;
        fold_kernel<<<(foldN + 255) / 256, 256, 0, stream>>>(Wk, bk, Wv, bv, a_rel, m_rel, wfT,
                                                             bfold, L);
    }

    // ---- merged CSR build ----
    {
        Csr3 P;
        int Etot = 0;
        int nbTot = 0;
        for (int r = 0; r < 3; ++r) {
            P.src[r] = edges[r];
            P.dst[r] = edges[r] + Er[r];
            P.E[r] = Er[r];
            P.indptr[r] = indptr[r];
            P.ssrc[r] = ssrc[r];
            P.Nd[r] = Ns[RD[r]];
            P.nb[r] = (P.Nd[r] + 1023) / 1024;
            Etot += Er[r];
            nbTot += P.nb[r];
        }
        P.cnt = cnt3;
        P.texcl = texcl3;
        P.bsums = bsums3;
        P.stride = Nmax;
        hipMemsetAsync(cnt3, 0, (size_t)3 * Nmax * 4, stream);
        hist3_kernel<<<(Etot + 255) / 256, 256, 0, stream>>>(P, Etot);
        scanA3_kernel<<<nbTot, 1024, 0, stream>>>(P);
        scanB3_kernel<<<3, 64, 0, stream>>>(P);
        scanC3_kernel<<<nbTot, 1024, 0, stream>>>(P);
        scatter3_kernel<<<(Etot + 255) / 256, 256, 0, stream>>>(P, Etot);
    }

    const int nb0 = (N0 + 127) / 128, nb1 = (N1 + 127) / 128;

    // ---- input projection (both types, one dispatch) ----
    gemm_dual<64, 1, 1><<<nb0 + nb1, 256, 0, stream>>>(
        x[0], winT, bin[0], h[0], N0, nullptr, nullptr,
        x[1], winT + 8192, bin[1], h[1], N1, nullptr, nullptr, nb0);

    // ---- layers ----
    for (int l = 0; l < L; ++l) {
        {
            QKVJobs J0{};
            J0.BT[0] = wqT + (size_t)(l * 2 + 0) * 16384;
            J0.bias[0] = bq + (size_t)(l * 2 + 0) * 128;
            J0.outBf[0] = q[0]; J0.outF8[0] = nullptr; J0.f8off[0] = 0;
            int fk0 = (l * 3 + 0) * 2, fk2 = (l * 3 + 2) * 2;
            J0.BT[1] = wfT + (size_t)fk0 * 16384;       J0.bias[1] = bfold + (size_t)fk0 * 128;
            J0.outBf[1] = nullptr; J0.outF8[1] = kv8[0]; J0.f8off[1] = 0;
            J0.BT[2] = wfT + (size_t)(fk0 + 1) * 16384; J0.bias[2] = bfold + (size_t)(fk0 + 1) * 128;
            J0.outBf[2] = nullptr; J0.outF8[2] = kv8[0]; J0.f8off[2] = 4;
            J0.BT[3] = wfT + (size_t)fk2 * 16384;       J0.bias[3] = bfold + (size_t)fk2 * 128;
            J0.outBf[3] = nullptr; J0.outF8[3] = kv8[2]; J0.f8off[3] = 0;
            J0.BT[4] = wfT + (size_t)(fk2 + 1) * 16384; J0.bias[4] = bfold + (size_t)(fk2 + 1) * 128;
            J0.outBf[4] = nullptr; J0.outF8[4] = kv8[2]; J0.f8off[4] = 4;
            QKVJobs J1{};
            J1.BT[0] = wqT + (size_t)(l * 2 + 1) * 16384;
            J1.bias[0] = bq + (size_t)(l * 2 + 1) * 128;
            J1.outBf[0] = q[1]; J1.outF8[0] = nullptr; J1.f8off[0] = 0;
            int fk1 = (l * 3 + 1) * 2;
            J1.BT[1] = wfT + (size_t)fk1 * 16384;       J1.bias[1] = bfold + (size_t)fk1 * 128;
            J1.outBf[1] = nullptr; J1.outF8[1] = kv8[1]; J1.f8off[1] = 0;
            J1.BT[2] = wfT + (size_t)(fk1 + 1) * 16384; J1.bias[2] = bfold + (size_t)(fk1 + 1) * 128;
            J1.outBf[2] = nullptr; J1.outF8[2] = kv8[1]; J1.f8off[2] = 4;
            gemm_qkv2<<<nb0 + nb1, 256, 0, stream>>>(h[0], J0, N0, 5, nb0, h[1], J1, N1, 3);
        }
        // fused attention (all relations, both dst types, 2 dsts per wave)
        {
            int waves = ((N0 + 1) >> 1) + ((N1 + 1) >> 1);
            attn_fused<<<(waves + 3) / 4, 256, 0, stream>>>(
                q[0], q[1], kv8[0], kv8[1], kv8[2], indptr[0], ssrc[0], indptr[1], ssrc[1],
                indptr[2], ssrc[2], agg[0], agg[1], p_rel + (size_t)(l * 3 + 0) * 8,
                p_rel + (size_t)(l * 3 + 1) * 8, p_rel + (size_t)(l * 3 + 2) * 8, N0, N1);
        }
        // output projection + skip (both types, one dispatch)
        gemm_dual<128, 2, 1><<<nb0 + nb1, 256, 0, stream>>>(
            agg[0], waT + (size_t)(l * 2 + 0) * 16384, ba + (size_t)(l * 2 + 0) * 128, h[0], N0,
            h[0], skip + (size_t)(l * 2 + 0),
            agg[1], waT + (size_t)(l * 2 + 1) * 16384, ba + (size_t)(l * 2 + 1) * 128, h[1], N1,
            h[1], skip + (size_t)(l * 2 + 1), nb0);
    }

    // ---- readout ----
    hipMemsetAsync(gsum, 0, 128 * 4, stream);
    colsum_kernel<<<512, 128, 0, stream>>>(h[0], gsum, N0);
    final_kernel<<<1, 128, 0, stream>>>(gsum, Wc1, bc1, Wc2, bc2, (float*)d_out,
                                        1.0f / (float)N0);
}

// Round 6
// 672.715 us; speedup vs baseline: 2.5422x; 1.0529x over previous
//
#include <hip/hip_runtime.h>
#include <hip/hip_fp8.h>
#include <math.h>

typedef __attribute__((ext_vector_type(8))) short short8v;   // 8 x bf16 (4 VGPRs)
typedef __attribute__((ext_vector_type(4))) float f32x4;
typedef __attribute__((ext_vector_type(2))) float f32x2;

__device__ __forceinline__ float bf2f(unsigned short u) {
    union { unsigned int i; float f; } x; x.i = ((unsigned int)u) << 16; return x.f;
}
__device__ __forceinline__ unsigned short f2bf(float f) {
    union { float f; unsigned int i; } x; x.f = f;
    unsigned int r = x.i + 0x7fffu + ((x.i >> 16) & 1u);
    return (unsigned short)(r >> 16);
}
__device__ __forceinline__ unsigned char f2fp8(float f) {
    __hip_fp8_e4m3 t(f);
    return (unsigned char)t.__x;
}
__device__ __forceinline__ float gelu_exact(float x) {
    return 0.5f * x * (1.0f + erff(x * 0.70710678118654752f));
}

// ============ bf16 MFMA GEMM body (input/output projections) ============
template <int K, int MODE, int ASRC>
__device__ __forceinline__ void gemm_body(
    const void* __restrict__ Aptr, const unsigned short* __restrict__ BT,
    const float* __restrict__ bias, unsigned short* __restrict__ Cout, int M,
    const unsigned short* __restrict__ hprev, const float* __restrict__ skipp, int blk) {
    __shared__ short As[128 * K];
    __shared__ short Bs[128 * K];
    const int tid = threadIdx.x;
    const int row0 = blk * 128;
    const int CH = K / 8;

#pragma unroll
    for (int i = 0; i < (128 * CH) / 256; ++i) {
        int idx = tid + i * 256;
        int r = idx / CH, c = idx % CH;
        int gr = row0 + r;
        short8v val = {0, 0, 0, 0, 0, 0, 0, 0};
        if (gr < M) {
            if (ASRC == 0) {
                val = *reinterpret_cast<const short8v*>(
                    (const unsigned short*)Aptr + (size_t)gr * K + c * 8);
            } else {
                const float* Af = (const float*)Aptr;
                float4 f0 = *reinterpret_cast<const float4*>(Af + (size_t)gr * K + c * 8);
                float4 f1 = *reinterpret_cast<const float4*>(Af + (size_t)gr * K + c * 8 + 4);
                float fa[8] = {f0.x, f0.y, f0.z, f0.w, f1.x, f1.y, f1.z, f1.w};
#pragma unroll
                for (int u = 0; u < 8; ++u) {
                    float fv = fa[u];
                    if (MODE == 2) fv = gelu_exact(fv);
                    val[u] = (short)f2bf(fv);
                }
            }
        }
        *reinterpret_cast<short8v*>((char*)As + r * (2 * K) + ((c * 16) ^ ((r & 7) << 4))) = val;
    }
#pragma unroll
    for (int i = 0; i < (128 * CH) / 256; ++i) {
        int idx = tid + i * 256;
        int r = idx / CH, c = idx % CH;
        short8v val = *reinterpret_cast<const short8v*>(BT + (size_t)r * K + c * 8);
        *reinterpret_cast<short8v*>((char*)Bs + r * (2 * K) + ((c * 16) ^ ((r & 7) << 4))) = val;
    }
    __syncthreads();

    const int lane = tid & 63, wid = tid >> 6;
    const int wr = wid >> 1, wc = wid & 1;
    const int lr = lane & 15, lg = lane >> 4;
    const int swz = (lr & 7) << 4;
    f32x4 acc[4][4];
    f32x4 z4 = {0.f, 0.f, 0.f, 0.f};
#pragma unroll
    for (int mi = 0; mi < 4; ++mi)
#pragma unroll
        for (int ni = 0; ni < 4; ++ni) acc[mi][ni] = z4;

#pragma unroll
    for (int ks = 0; ks < K / 32; ++ks) {
        int kc = ks * 64 + lg * 16;
        short8v a[4], b[4];
#pragma unroll
        for (int mi = 0; mi < 4; ++mi) {
            int r = wr * 64 + mi * 16 + lr;
            a[mi] = *reinterpret_cast<const short8v*>((char*)As + r * (2 * K) + (kc ^ swz));
        }
#pragma unroll
        for (int ni = 0; ni < 4; ++ni) {
            int r = wc * 64 + ni * 16 + lr;
            b[ni] = *reinterpret_cast<const short8v*>((char*)Bs + r * (2 * K) + (kc ^ swz));
        }
#pragma unroll
        for (int mi = 0; mi < 4; ++mi)
#pragma unroll
            for (int ni = 0; ni < 4; ++ni)
                acc[mi][ni] =
                    __builtin_amdgcn_mfma_f32_16x16x32_bf16(a[mi], b[ni], acc[mi][ni], 0, 0, 0);
    }

    float beta = 0.f;
    if (MODE == 2) beta = 1.f / (1.f + expf(-skipp[0]));
#pragma unroll
    for (int mi = 0; mi < 4; ++mi) {
#pragma unroll
        for (int ni = 0; ni < 4; ++ni) {
            int col = wc * 64 + ni * 16 + lr;
            float bv = bias[col];
#pragma unroll
            for (int j = 0; j < 4; ++j) {
                int gr = row0 + wr * 64 + mi * 16 + lg * 4 + j;
                if (gr < M) {
                    float v = acc[mi][ni][j] + bv;
                    if (MODE == 1) v = fmaxf(v, 0.f);
                    if (MODE == 2) v = beta * v + (1.f - beta) * bf2f(hprev[(size_t)gr * 128 + col]);
                    Cout[(size_t)gr * 128 + col] = f2bf(v);
                }
            }
        }
    }
}

template <int K, int MODE, int ASRC>
__global__ __launch_bounds__(256) void gemm_dual(
    const void* A0, const unsigned short* BT0, const float* b0, unsigned short* C0, int M0,
    const unsigned short* hp0, const float* sk0,
    const void* A1, const unsigned short* BT1, const float* b1, unsigned short* C1, int M1,
    const unsigned short* hp1, const float* sk1, int nb0) {
    if ((int)blockIdx.x < nb0)
        gemm_body<K, MODE, ASRC>(A0, BT0, b0, C0, M0, hp0, sk0, blockIdx.x);
    else
        gemm_body<K, MODE, ASRC>(A1, BT1, b1, C1, M1, hp1, sk1, blockIdx.x - nb0);
}

// ============ fused QKV GEMM: one A-tile, up to 5 B-matrices ============
// fp8 out layout: row = 32 chunks x 8B; chunk c bytes [8c..8c+3] = K cols 4c..4c+3,
// bytes [8c+4..8c+7] = V cols 4c..4c+3.  f8off: 0 for K, 4 for V.
struct QKVJobs {
    const unsigned short* BT[5];
    const float* bias[5];
    unsigned short* outBf[5];
    unsigned char* outF8[5];
    int f8off[5];
};

__device__ __forceinline__ void qkv_body(const unsigned short* __restrict__ A,
                                         const QKVJobs& J, int M, int nj, int blk) {
    __shared__ short As[128 * 128];
    __shared__ short Bs[128 * 128];
    const int tid = threadIdx.x;
    const int row0 = blk * 128;

    short8v breg[8];
#pragma unroll
    for (int i = 0; i < 8; ++i) {
        int idx = tid + i * 256;
        int r = idx >> 4, c = idx & 15;
        breg[i] = *reinterpret_cast<const short8v*>(J.BT[0] + (size_t)r * 128 + c * 8);
    }
#pragma unroll
    for (int i = 0; i < 8; ++i) {
        int idx = tid + i * 256;
        int r = idx >> 4, c = idx & 15;
        int gr = row0 + r;
        short8v val = {0, 0, 0, 0, 0, 0, 0, 0};
        if (gr < M) val = *reinterpret_cast<const short8v*>(A + (size_t)gr * 128 + c * 8);
        *reinterpret_cast<short8v*>((char*)As + r * 256 + ((c * 16) ^ ((r & 7) << 4))) = val;
    }
#pragma unroll
    for (int i = 0; i < 8; ++i) {
        int idx = tid + i * 256;
        int r = idx >> 4, c = idx & 15;
        *reinterpret_cast<short8v*>((char*)Bs + r * 256 + ((c * 16) ^ ((r & 7) << 4))) = breg[i];
    }

    const int lane = tid & 63, wid = tid >> 6;
    const int wr = wid >> 1, wc = wid & 1;
    const int lr = lane & 15, lg = lane >> 4;
    const int swz = (lr & 7) << 4;

    for (int m = 0; m < nj; ++m) {
        if (m + 1 < nj) {
#pragma unroll
            for (int i = 0; i < 8; ++i) {
                int idx = tid + i * 256;
                int r = idx >> 4, c = idx & 15;
                breg[i] = *reinterpret_cast<const short8v*>(J.BT[m + 1] + (size_t)r * 128 + c * 8);
            }
        }
        __syncthreads();

        f32x4 acc[4][4];
        f32x4 z4 = {0.f, 0.f, 0.f, 0.f};
#pragma unroll
        for (int mi = 0; mi < 4; ++mi)
#pragma unroll
            for (int ni = 0; ni < 4; ++ni) acc[mi][ni] = z4;

#pragma unroll
        for (int ks = 0; ks < 4; ++ks) {
            int kc = ks * 64 + lg * 16;
            short8v a[4], b[4];
#pragma unroll
            for (int mi = 0; mi < 4; ++mi) {
                int r = wr * 64 + mi * 16 + lr;
                a[mi] = *reinterpret_cast<const short8v*>((char*)As + r * 256 + (kc ^ swz));
            }
#pragma unroll
            for (int ni = 0; ni < 4; ++ni) {
                int r = wc * 64 + ni * 16 + lr;
                b[ni] = *reinterpret_cast<const short8v*>((char*)Bs + r * 256 + (kc ^ swz));
            }
#pragma unroll
            for (int mi = 0; mi < 4; ++mi)
#pragma unroll
                for (int ni = 0; ni < 4; ++ni)
                    acc[mi][ni] = __builtin_amdgcn_mfma_f32_16x16x32_bf16(a[mi], b[ni],
                                                                          acc[mi][ni], 0, 0, 0);
        }
        __syncthreads();
        if (m + 1 < nj) {
#pragma unroll
            for (int i = 0; i < 8; ++i) {
                int idx = tid + i * 256;
                int r = idx >> 4, c = idx & 15;
                *reinterpret_cast<short8v*>((char*)Bs + r * 256 + ((c * 16) ^ ((r & 7) << 4))) =
                    breg[i];
            }
        }

        unsigned short* outBf = J.outBf[m];
        unsigned char* outF8 = J.outF8[m];
        int off = J.f8off[m];
        const float* bias = J.bias[m];
#pragma unroll
        for (int mi = 0; mi < 4; ++mi) {
#pragma unroll
            for (int ni = 0; ni < 4; ++ni) {
                int col = wc * 64 + ni * 16 + lr;
                float bv = bias[col];
                int bpos = ((col & 124) << 1) + off + (col & 3);
#pragma unroll
                for (int j = 0; j < 4; ++j) {
                    int gr = row0 + wr * 64 + mi * 16 + lg * 4 + j;
                    if (gr < M) {
                        float v = acc[mi][ni][j] + bv;
                        if (outBf) outBf[(size_t)gr * 128 + col] = f2bf(v);
                        else outF8[(size_t)gr * 256 + bpos] = f2fp8(v);
                    }
                }
            }
        }
    }
}

__global__ __launch_bounds__(256) void gemm_qkv2(const unsigned short* A0, QKVJobs J0, int M0,
                                                 int nj0, int nb0, const unsigned short* A1,
                                                 QKVJobs J1, int M1, int nj1) {
    if ((int)blockIdx.x < nb0) qkv_body(A0, J0, M0, nj0, blockIdx.x);
    else qkv_body(A1, J1, M1, nj1, blockIdx.x - nb0);
}

// ============ weight prep ============
__global__ void convT_kernel(const float* __restrict__ Win0, const float* __restrict__ Win1,
                             const float* __restrict__ Wq, const float* __restrict__ Wa,
                             unsigned short* __restrict__ winT, unsigned short* __restrict__ wqT,
                             unsigned short* __restrict__ waT, int nmat) {
    int gid = blockIdx.x * 256 + threadIdx.x;
    if (gid < 2 * 8192) {
        int m = gid >> 13, idx = gid & 8191;
        int n = idx >> 6, k = idx & 63;
        const float* W = m ? Win1 : Win0;
        winT[gid] = f2bf(W[(size_t)k * 128 + n]);
        return;
    }
    int g = gid - 2 * 8192;
    if (g < nmat * 16384) {
        int mat = g >> 14, idx = g & 16383;
        int n = idx >> 7, k = idx & 127;
        wqT[g] = f2bf(Wq[(size_t)mat * 16384 + (size_t)k * 128 + n]);
        return;
    }
    g -= nmat * 16384;
    if (g < nmat * 16384) {
        int mat = g >> 14, idx = g & 16383;
        int n = idx >> 7, k = idx & 127;
        waT[g] = f2bf(Wa[(size_t)mat * 16384 + (size_t)k * 128 + n]);
    }
}

// ============ relation fold ============
__global__ void fold_kernel(const float* __restrict__ Wk, const float* __restrict__ bk,
                            const float* __restrict__ Wv, const float* __restrict__ bv,
                            const float* __restrict__ a_rel, const float* __restrict__ m_rel,
                            unsigned short* __restrict__ wfT, float* __restrict__ bfold, int L) {
    const int RSarr[3] = {0, 1, 0};
    int gid = blockIdx.x * 256 + threadIdx.x;
    int NW = L * 6 * 16384;
    if (gid < NW) {
        int fold = gid >> 14, idx = gid & 16383;
        int col = idx >> 7, i = idx & 127;
        int kv = fold & 1, lr = fold >> 1, l = lr / 3, r = lr % 3;
        int s = RSarr[r];
        const float* W = (kv ? Wv : Wk) + (size_t)(l * 2 + s) * 16384;
        const float* rel = (kv ? m_rel : a_rel) + (size_t)(l * 3 + r) * 2048;
        int hh = col >> 4, f = col & 15;
        float sacc = 0.f;
#pragma unroll
        for (int d = 0; d < 16; ++d)
            sacc += W[(size_t)i * 128 + hh * 16 + d] * rel[hh * 256 + d * 16 + f];
        wfT[gid] = f2bf(sacc);
        return;
    }
    int g = gid - NW;
    if (g >= L * 6 * 128) return;
    int fold = g >> 7, col = g & 127;
    int kv = fold & 1, lr = fold >> 1, l = lr / 3, r = lr % 3;
    int s = RSarr[r];
    const float* b = (kv ? bv : bk) + (size_t)(l * 2 + s) * 128;
    const float* rel = (kv ? m_rel : a_rel) + (size_t)(l * 3 + r) * 2048;
    int hh = col >> 4, f = col & 15;
    float sacc = 0.f;
#pragma unroll
    for (int d = 0; d < 16; ++d) sacc += b[hh * 16 + d] * rel[hh * 256 + d * 16 + f];
    bfold[fold * 128 + col] = sacc;
}

// ============ merged CSR build (all 3 relations) ============
struct Csr3 {
    const int* src[3];
    const int* dst[3];
    int E[3];
    int* cnt;      // 3*stride ints (later reused as cursor)
    int* texcl;    // 3*stride
    int* bsums;    // 3*64
    int* indptr[3];
    int* ssrc[3];
    int Nd[3];
    int nb[3];
    int stride;
};

__global__ void hist3_kernel(Csr3 P, int Etot) {
    int gid = blockIdx.x * 256 + threadIdx.x;
    if (gid >= Etot) return;
    int r = 0, off = gid;
    if (off >= P.E[0]) { off -= P.E[0]; r = 1; if (off >= P.E[1]) { off -= P.E[1]; r = 2; } }
    atomicAdd(&P.cnt[r * P.stride + P.dst[r][off]], 1);
}

__global__ __launch_bounds__(1024) void scanA3_kernel(Csr3 P) {
    __shared__ int s[1024];
    int b = blockIdx.x, r = 0;
    while (b >= P.nb[r]) { b -= P.nb[r]; ++r; }
    const int* cnt = P.cnt + r * P.stride;
    int* texcl = P.texcl + r * P.stride;
    int n = P.Nd[r];
    int t = threadIdx.x;
    int gid = b * 1024 + t;
    int x = (gid < n) ? cnt[gid] : 0;
    s[t] = x;
    __syncthreads();
    for (int off = 1; off < 1024; off <<= 1) {
        int v = (t >= off) ? s[t - off] : 0;
        __syncthreads();
        s[t] += v;
        __syncthreads();
    }
    if (gid < n) texcl[gid] = s[t] - x;
    if (t == 1023) P.bsums[r * 64 + b] = s[1023];
}

__global__ void scanB3_kernel(Csr3 P) {
    int r = blockIdx.x;
    if (threadIdx.x == 0) {
        int run = 0;
        for (int i = 0; i < P.nb[r]; ++i) {
            int t = P.bsums[r * 64 + i];
            P.bsums[r * 64 + i] = run;
            run += t;
        }
    }
}

__global__ __launch_bounds__(1024) void scanC3_kernel(Csr3 P) {
    int b = blockIdx.x, r = 0;
    while (b >= P.nb[r]) { b -= P.nb[r]; ++r; }
    int n = P.Nd[r];
    int gid = b * 1024 + threadIdx.x;
    if (gid < n) {
        int v = P.texcl[r * P.stride + gid] + P.bsums[r * 64 + b];
        P.indptr[r][gid] = v;
        P.cnt[r * P.stride + gid] = v;  // cursor
    }
    if (gid == 0) P.indptr[r][n] = P.E[r];
}

// ---- fallback scatter (generic N) ----
__global__ void scatter3_kernel(Csr3 P, int Etot) {
    int gid = blockIdx.x * 256 + threadIdx.x;
    if (gid >= Etot) return;
    int r = 0, off = gid;
    if (off >= P.E[0]) { off -= P.E[0]; r = 1; if (off >= P.E[1]) { off -= P.E[1]; r = 2; } }
    int d = P.dst[r][off];
    int p = atomicAdd(&P.cnt[r * P.stride + d], 1);
    P.ssrc[r][p] = P.src[r][off];
}

// ---- fast path (N<=65536): bucket partition + L2-local fine scatter ----
// Bucket b = dst>>10 (<=64 buckets). pbuf regions aligned with indptr: bucket b
// occupies [indptr[b<<10], indptr[min((b+1)<<10,Nd)]) -- same as final ssrc layout.
__global__ void gcur_init_kernel(Csr3 P, int* __restrict__ gcur) {
    int t = threadIdx.x;  // 256 >= 192
    if (t >= 192) return;
    int r = t >> 6, b = t & 63;
    int nbk = (P.Nd[r] + 1023) >> 10;
    gcur[t] = (b < nbk) ? P.indptr[r][b << 10] : 0;
}

#define PA_TILE 4096
#define PA_BLKS 64
__global__ __launch_bounds__(256) void partA_kernel(Csr3 P, unsigned int* __restrict__ pb0,
                                                    unsigned int* __restrict__ pb1,
                                                    unsigned int* __restrict__ pb2,
                                                    int* __restrict__ gcur) {
    unsigned int* pbuf[3] = {pb0, pb1, pb2};
    const int r = blockIdx.x / PA_BLKS;
    const int blk = blockIdx.x % PA_BLKS;
    const int tid = threadIdx.x;
    const int* __restrict__ srcp = P.src[r];
    const int* __restrict__ dstp = P.dst[r];
    const int E = P.E[r];
    unsigned int* __restrict__ out = pbuf[r];
    __shared__ unsigned int stage[PA_TILE];
    __shared__ unsigned char bkt[PA_TILE];
    __shared__ int lcnt[64], lofs[64], lbase[64];

    for (int t0 = blk * PA_TILE; t0 < E; t0 += PA_BLKS * PA_TILE) {
        int cnt = E - t0;
        if (cnt > PA_TILE) cnt = PA_TILE;
        if (tid < 64) lcnt[tid] = 0;
        __syncthreads();
        unsigned int pk[16];
        int lp[16];
#pragma unroll
        for (int j = 0; j < 16; ++j) {
            int i = tid + j * 256;
            if (i < cnt) {
                int s = srcp[t0 + i];
                int d = dstp[t0 + i];
                pk[j] = ((unsigned int)d << 16) | (unsigned int)s;
                lp[j] = atomicAdd(&lcnt[d >> 10], 1);
            }
        }
        __syncthreads();
        if (tid == 0) {
            int run = 0;
            for (int b = 0; b < 64; ++b) { lofs[b] = run; run += lcnt[b]; }
        }
        __syncthreads();
        if (tid < 64 && lcnt[tid] > 0) lbase[tid] = atomicAdd(&gcur[r * 64 + tid], lcnt[tid]);
        __syncthreads();
#pragma unroll
        for (int j = 0; j < 16; ++j) {
            int i = tid + j * 256;
            if (i < cnt) {
                int b = pk[j] >> 26;
                int sp = lofs[b] + lp[j];
                stage[sp] = pk[j];
                bkt[sp] = (unsigned char)b;
            }
        }
        __syncthreads();
        for (int k = tid; k < cnt; k += 256) {
            int b = bkt[k];
            out[lbase[b] + (k - lofs[b])] = stage[k];
        }
        __syncthreads();
    }
}

__global__ __launch_bounds__(256) void partB_kernel(Csr3 P, const unsigned int* __restrict__ pb0,
                                                    const unsigned int* __restrict__ pb1,
                                                    const unsigned int* __restrict__ pb2) {
    const unsigned int* pbuf[3] = {pb0, pb1, pb2};
    int r = blockIdx.x >> 6, b = blockIdx.x & 63;
    int Nd = P.Nd[r];
    int nbk = (Nd + 1023) >> 10;
    if (b >= nbk) return;
    int d1 = (b + 1) << 10;
    if (d1 > Nd) d1 = Nd;
    int lo = P.indptr[r][b << 10];
    int hi = P.indptr[r][d1];
    const unsigned int* __restrict__ pin = pbuf[r];
    int* __restrict__ cursor = P.cnt + r * P.stride;
    int* __restrict__ out = P.ssrc[r];
    for (int i = lo + (int)threadIdx.x; i < hi; i += 256) {
        unsigned int pk = pin[i];
        int d = pk >> 16;
        int p = atomicAdd(&cursor[d], 1);
        out[p] = (int)(pk & 0xffffu);
    }
}

// ============ attention: 2 dsts per wave (32 lanes each), fp8 interleaved kv ============
__device__ __forceinline__ void run_chain(const unsigned char* __restrict__ kv,
                                          const int* __restrict__ ss, int beg, int n,
                                          const float qf[4], float psc, int lq, int lhb,
                                          float& ssum, float4& acc) {
    if (n <= 0) return;
    int bat = (lq < n) ? ss[beg + lq] : 0;
    int s0 = __shfl(bat, lhb);
    uint2 cur = *reinterpret_cast<const uint2*>(kv + (size_t)s0 * 256 + lq * 8);
    for (int i = 0; i < n; ++i) {
        uint2 nxt = make_uint2(0u, 0u);
        int j = i + 1;
        if (j < n) {
            int ph = j & 31;
            if (ph == 0) bat = (j + lq < n) ? ss[beg + j + lq] : 0;
            int s = __shfl(bat, lhb + ph);
            nxt = *reinterpret_cast<const uint2*>(kv + (size_t)s * 256 + lq * 8);
        }
        f32x2 klo = __builtin_amdgcn_cvt_pk_f32_fp8(cur.x, false);
        f32x2 khi = __builtin_amdgcn_cvt_pk_f32_fp8(cur.x, true);
        float t = qf[0] * klo[0] + qf[1] * klo[1] + qf[2] * khi[0] + qf[3] * khi[1];
        t += __shfl_xor(t, 1);
        t += __shfl_xor(t, 2);
        float e = fminf(fmaxf(t * psc, -40.f), 40.f);
        float w = exp2f(e);
        f32x2 vlo = __builtin_amdgcn_cvt_pk_f32_fp8(cur.y, false);
        f32x2 vhi = __builtin_amdgcn_cvt_pk_f32_fp8(cur.y, true);
        ssum += w;
        acc.x += w * vlo[0];
        acc.y += w * vlo[1];
        acc.z += w * vhi[0];
        acc.w += w * vhi[1];
        cur = nxt;
    }
}

__global__ __launch_bounds__(256) void attn_fused(
    const unsigned short* __restrict__ q0, const unsigned short* __restrict__ q1,
    const unsigned char* __restrict__ kvA, const unsigned char* __restrict__ kvB,
    const unsigned char* __restrict__ kvC,
    const int* __restrict__ ipA, const int* __restrict__ ssA,
    const int* __restrict__ ipB, const int* __restrict__ ssB,
    const int* __restrict__ ipC, const int* __restrict__ ssC,
    float* __restrict__ agg0, float* __restrict__ agg1,
    const float* __restrict__ prA, const float* __restrict__ prB,
    const float* __restrict__ prC, int N0, int N1) {
    const int wave = (blockIdx.x * blockDim.x + threadIdx.x) >> 6;
    const int lane = threadIdx.x & 63;
    const int lq = lane & 31;
    const int lhb = lane & 32;        // half base for shfl
    const int head = lq >> 2;
    const float LOG2E = 1.4426950408889634f;
    const int P0 = (N0 + 1) >> 1;
    const int P1 = (N1 + 1) >> 1;
    if (wave >= P0 + P1) return;

    if (wave < P0) {
        int dst = wave * 2 + (lhb >> 5);
        bool act = dst < N0;
        float qf[4] = {0.f, 0.f, 0.f, 0.f};
        int b1 = 0, n1 = 0, b2 = 0, n2 = 0;
        if (act) {
            ushort4 qv = *reinterpret_cast<const ushort4*>(q0 + (size_t)dst * 128 + lq * 4);
            qf[0] = bf2f(qv.x); qf[1] = bf2f(qv.y); qf[2] = bf2f(qv.z); qf[3] = bf2f(qv.w);
            b1 = ipA[dst]; n1 = ipA[dst + 1] - b1;
            b2 = ipB[dst]; n2 = ipB[dst + 1] - b2;
        }
        float pA = prA[head] * 0.25f * LOG2E;
        float pB = prB[head] * 0.25f * LOG2E;
        float s1 = 0.f, s2 = 0.f;
        float4 a1 = make_float4(0.f, 0.f, 0.f, 0.f);
        float4 a2 = make_float4(0.f, 0.f, 0.f, 0.f);
        run_chain(kvA, ssA, b1, n1, qf, pA, lq, lhb, s1, a1);
        run_chain(kvB, ssB, b2, n2, qf, pB, lq, lhb, s2, a2);
        if (act) {
            float i1 = 1.f / fmaxf(s1, 1e-16f);
            float i2 = 1.f / fmaxf(s2, 1e-16f);
            float4 r = make_float4(a1.x * i1 + a2.x * i2, a1.y * i1 + a2.y * i2,
                                   a1.z * i1 + a2.z * i2, a1.w * i1 + a2.w * i2);
            *reinterpret_cast<float4*>(agg0 + (size_t)dst * 128 + lq * 4) = r;
        }
    } else {
        int dst = (wave - P0) * 2 + (lhb >> 5);
        bool act = dst < N1;
        float qf[4] = {0.f, 0.f, 0.f, 0.f};
        int b1 = 0, n1 = 0;
        if (act) {
            ushort4 qv = *reinterpret_cast<const ushort4*>(q1 + (size_t)dst * 128 + lq * 4);
            qf[0] = bf2f(qv.x); qf[1] = bf2f(qv.y); qf[2] = bf2f(qv.z); qf[3] = bf2f(qv.w);
            b1 = ipC[dst]; n1 = ipC[dst + 1] - b1;
        }
        float pC = prC[head] * 0.25f * LOG2E;
        float s1 = 0.f;
        float4 a1 = make_float4(0.f, 0.f, 0.f, 0.f);
        run_chain(kvC, ssC, b1, n1, qf, pC, lq, lhb, s1, a1);
        if (act) {
            float i1 = 1.f / fmaxf(s1, 1e-16f);
            float4 r = make_float4(a1.x * i1, a1.y * i1, a1.z * i1, a1.w * i1);
            *reinterpret_cast<float4*>(agg1 + (size_t)dst * 128 + lq * 4) = r;
        }
    }
}

// ============ readout ============
__global__ void colsum_kernel(const unsigned short* __restrict__ h, float* __restrict__ gsum,
                              int M) {
    int c = threadIdx.x;
    float s = 0.f;
    for (int r = blockIdx.x; r < M; r += gridDim.x) s += bf2f(h[(size_t)r * 128 + c]);
    atomicAdd(&gsum[c], s);
}

__global__ void final_kernel(const float* __restrict__ gsum, const float* __restrict__ Wc1,
                             const float* __restrict__ bc1, const float* __restrict__ Wc2,
                             const float* __restrict__ bc2, float* __restrict__ out,
                             float invM) {
    __shared__ float g[128];
    __shared__ float red[128];
    int t = threadIdx.x;
    g[t] = gsum[t] * invM;
    __syncthreads();
    float acc = bc1[t];
    for (int k = 0; k < 128; ++k) acc += g[k] * Wc1[k * 128 + t];
    float zv = fmaxf(acc, 0.f);
    red[t] = zv * Wc2[t];
    __syncthreads();
    for (int off = 64; off > 0; off >>= 1) {
        if (t < off) red[t] += red[t + off];
        __syncthreads();
    }
    if (t == 0) out[0] = 1.f / (1.f + expf(-(red[0] + bc2[0])));
}

extern "C" void kernel_launch(void* const* d_in, const int* in_sizes, int n_in,
                              void* d_out, int out_size, void* d_ws, size_t ws_size,
                              hipStream_t stream) {
    const float* x[2] = {(const float*)d_in[0], (const float*)d_in[1]};
    const int* edges[3] = {(const int*)d_in[2], (const int*)d_in[3], (const int*)d_in[4]};
    const float* Win[2] = {(const float*)d_in[5], (const float*)d_in[7]};
    const float* bin[2] = {(const float*)d_in[6], (const float*)d_in[8]};
    const float* Wk = (const float*)d_in[9];
    const float* bk = (const float*)d_in[10];
    const float* Wq = (const float*)d_in[11];
    const float* bq = (const float*)d_in[12];
    const float* Wv = (const float*)d_in[13];
    const float* bv = (const float*)d_in[14];
    const float* a_rel = (const float*)d_in[15];
    const float* m_rel = (const float*)d_in[16];
    const float* p_rel = (const float*)d_in[17];
    const float* Wa = (const float*)d_in[18];
    const float* ba = (const float*)d_in[19];
    const float* skip = (const float*)d_in[20];
    const float* Wc1 = (const float*)d_in[21];
    const float* bc1 = (const float*)d_in[22];
    const float* Wc2 = (const float*)d_in[23];
    const float* bc2 = (const float*)d_in[24];

    const int N0 = in_sizes[0] / 64;
    const int N1 = in_sizes[1] / 64;
    const int L = in_sizes[9] / (2 * 128 * 128);
    const int Ns[2] = {N0, N1};
    const int RD[3] = {0, 0, 1};
    const int Nmax = (N0 > N1) ? N0 : N1;

    char* p = (char*)d_ws;
    auto alloc = [&](size_t bytes) -> void* {
        void* r = (void*)p;
        p += (bytes + 255) & ~(size_t)255;
        return r;
    };
    unsigned short* h[2];
    unsigned short* q[2];
    float* agg[2];
    h[0] = (unsigned short*)alloc((size_t)N0 * 128 * 2);
    h[1] = (unsigned short*)alloc((size_t)N1 * 128 * 2);
    q[0] = (unsigned short*)alloc((size_t)N0 * 128 * 2);
    q[1] = (unsigned short*)alloc((size_t)N1 * 128 * 2);
    agg[0] = (float*)alloc((size_t)N0 * 128 * 4);
    agg[1] = (float*)alloc((size_t)N1 * 128 * 4);
    unsigned char* kv8[3];
    for (int r = 0; r < 3; ++r) kv8[r] = (unsigned char*)alloc((size_t)Nmax * 256);
    int* indptr[3];
    int* ssrc[3];
    int Er[3];
    for (int r = 0; r < 3; ++r) {
        Er[r] = in_sizes[2 + r] / 2;
        indptr[r] = (int*)alloc((size_t)(Ns[RD[r]] + 1) * 4);
        ssrc[r] = (int*)alloc((size_t)Er[r] * 4);
    }
    unsigned int* pbuf[3];
    for (int r = 0; r < 3; ++r) pbuf[r] = (unsigned int*)alloc((size_t)Er[r] * 4);
    int* cnt3 = (int*)alloc((size_t)3 * Nmax * 4);
    int* texcl3 = (int*)alloc((size_t)3 * Nmax * 4);
    int* bsums3 = (int*)alloc(3 * 64 * 4);
    int* gcur = (int*)alloc(3 * 64 * 4);
    unsigned short* winT = (unsigned short*)alloc(2 * 8192 * 2);
    unsigned short* wqT = (unsigned short*)alloc((size_t)L * 2 * 16384 * 2);
    unsigned short* waT = (unsigned short*)alloc((size_t)L * 2 * 16384 * 2);
    unsigned short* wfT = (unsigned short*)alloc((size_t)L * 6 * 16384 * 2);
    float* bfold = (float*)alloc((size_t)L * 6 * 128 * 4);
    float* gsum = (float*)alloc(128 * 4);

    // ---- weight prep ----
    {
        int nmat = L * 2;
        int convN = 2 * 8192 + 2 * nmat * 16384;
        convT_kernel<<<(convN + 255) / 256, 256, 0, stream>>>(Win[0], Win[1], Wq, Wa, winT, wqT,
                                                              waT, nmat);
        int foldN = L * 6 * 16384 + L * 6 * 128;
        fold_kernel<<<(foldN + 255) / 256, 256, 0, stream>>>(Wk, bk, Wv, bv, a_rel, m_rel, wfT,
                                                             bfold, L);
    }

    // ---- merged CSR build ----
    {
        Csr3 P;
        int Etot = 0;
        int nbTot = 0;
        for (int r = 0; r < 3; ++r) {
            P.src[r] = edges[r];
            P.dst[r] = edges[r] + Er[r];
            P.E[r] = Er[r];
            P.indptr[r] = indptr[r];
            P.ssrc[r] = ssrc[r];
            P.Nd[r] = Ns[RD[r]];
            P.nb[r] = (P.Nd[r] + 1023) / 1024;
            Etot += Er[r];
            nbTot += P.nb[r];
        }
        P.cnt = cnt3;
        P.texcl = texcl3;
        P.bsums = bsums3;
        P.stride = Nmax;
        hipMemsetAsync(cnt3, 0, (size_t)3 * Nmax * 4, stream);
        hist3_kernel<<<(Etot + 255) / 256, 256, 0, stream>>>(P, Etot);
        scanA3_kernel<<<nbTot, 1024, 0, stream>>>(P);
        scanB3_kernel<<<3, 64, 0, stream>>>(P);
        scanC3_kernel<<<nbTot, 1024, 0, stream>>>(P);
        if (Nmax <= 65536) {
            gcur_init_kernel<<<1, 256, 0, stream>>>(P, gcur);
            partA_kernel<<<3 * PA_BLKS, 256, 0, stream>>>(P, pbuf[0], pbuf[1], pbuf[2], gcur);
            partB_kernel<<<3 * 64, 256, 0, stream>>>(P, pbuf[0], pbuf[1], pbuf[2]);
        } else {
            scatter3_kernel<<<(Etot + 255) / 256, 256, 0, stream>>>(P, Etot);
        }
    }

    const int nb0 = (N0 + 127) / 128, nb1 = (N1 + 127) / 128;

    // ---- input projection (both types, one dispatch) ----
    gemm_dual<64, 1, 1><<<nb0 + nb1, 256, 0, stream>>>(
        x[0], winT, bin[0], h[0], N0, nullptr, nullptr,
        x[1], winT + 8192, bin[1], h[1], N1, nullptr, nullptr, nb0);

    // ---- layers ----
    for (int l = 0; l < L; ++l) {
        {
            QKVJobs J0{};
            J0.BT[0] = wqT + (size_t)(l * 2 + 0) * 16384;
            J0.bias[0] = bq + (size_t)(l * 2 + 0) * 128;
            J0.outBf[0] = q[0]; J0.outF8[0] = nullptr; J0.f8off[0] = 0;
            int fk0 = (l * 3 + 0) * 2, fk2 = (l * 3 + 2) * 2;
            J0.BT[1] = wfT + (size_t)fk0 * 16384;       J0.bias[1] = bfold + (size_t)fk0 * 128;
            J0.outBf[1] = nullptr; J0.outF8[1] = kv8[0]; J0.f8off[1] = 0;
            J0.BT[2] = wfT + (size_t)(fk0 + 1) * 16384; J0.bias[2] = bfold + (size_t)(fk0 + 1) * 128;
            J0.outBf[2] = nullptr; J0.outF8[2] = kv8[0]; J0.f8off[2] = 4;
            J0.BT[3] = wfT + (size_t)fk2 * 16384;       J0.bias[3] = bfold + (size_t)fk2 * 128;
            J0.outBf[3] = nullptr; J0.outF8[3] = kv8[2]; J0.f8off[3] = 0;
            J0.BT[4] = wfT + (size_t)(fk2 + 1) * 16384; J0.bias[4] = bfold + (size_t)(fk2 + 1) * 128;
            J0.outBf[4] = nullptr; J0.outF8[4] = kv8[2]; J0.f8off[4] = 4;
            QKVJobs J1{};
            J1.BT[0] = wqT + (size_t)(l * 2 + 1) * 16384;
            J1.bias[0] = bq + (size_t)(l * 2 + 1) * 128;
            J1.outBf[0] = q[1]; J1.outF8[0] = nullptr; J1.f8off[0] = 0;
            int fk1 = (l * 3 + 1) * 2;
            J1.BT[1] = wfT + (size_t)fk1 * 16384;       J1.bias[1] = bfold + (size_t)fk1 * 128;
            J1.outBf[1] = nullptr; J1.outF8[1] = kv8[1]; J1.f8off[1] = 0;
            J1.BT[2] = wfT + (size_t)(fk1 + 1) * 16384; J1.bias[2] = bfold + (size_t)(fk1 + 1) * 128;
            J1.outBf[2] = nullptr; J1.outF8[2] = kv8[1]; J1.f8off[2] = 4;
            gemm_qkv2<<<nb0 + nb1, 256, 0, stream>>>(h[0], J0, N0, 5, nb0, h[1], J1, N1, 3);
        }
        // fused attention (all relations, both dst types, 2 dsts per wave)
        {
            int waves = ((N0 + 1) >> 1) + ((N1 + 1) >> 1);
            attn_fused<<<(waves + 3) / 4, 256, 0, stream>>>(
                q[0], q[1], kv8[0], kv8[1], kv8[2], indptr[0], ssrc[0], indptr[1], ssrc[1],
                indptr[2], ssrc[2], agg[0], agg[1], p_rel + (size_t)(l * 3 + 0) * 8,
                p_rel + (size_t)(l * 3 + 1) * 8, p_rel + (size_t)(l * 3 + 2) * 8, N0, N1);
        }
        // output projection + skip (both types, one dispatch)
        gemm_dual<128, 2, 1><<<nb0 + nb1, 256, 0, stream>>>(
            agg[0], waT + (size_t)(l * 2 + 0) * 16384, ba + (size_t)(l * 2 + 0) * 128, h[0], N0,
            h[0], skip + (size_t)(l * 2 + 0),
            agg[1], waT + (size_t)(l * 2 + 1) * 16384, ba + (size_t)(l * 2 + 1) * 128, h[1], N1,
            h[1], skip + (size_t)(l * 2 + 1), nb0);
    }

    // ---- readout ----
    hipMemsetAsync(gsum, 0, 128 * 4, stream);
    colsum_kernel<<<512, 128, 0, stream>>>(h[0], gsum, N0);
    final_kernel<<<1, 128, 0, stream>>>(gsum, Wc1, bc1, Wc2, bc2, (float*)d_out,
                                        1.0f / (float)N0);
}